// Round 1
// 51.479 us; speedup vs baseline: 1.1091x; 1.1091x over previous
//
#include <hip/hip_runtime.h>
#include <math.h>

#define B_ 4
#define K_ 512
#define N_ 4096
#define M_ 4

#define KTHREADS 512
#define SLOTS 8                 // slot = tid & 7
#define SEGS 64                 // seg  = tid >> 3
#define RPT 4                   // rows per thread (was 2): halves LDS reads per cand-row
#define ROWSB (SLOTS * RPT)     // 32 rows per block
#define CHUNK 1024
#define NCHUNK (N_ / CHUNK)     // 4
#define CPL (CHUNK / SEGS)      // 16 columns per lane per chunk

// ---------- sorting networks (exact top-8 multiset; lattice min/max only) ----------
__device__ __forceinline__ void sort8(float s[8]) {
#define CE_(a,b) { float lo_=fminf(s[a],s[b]); float hi_=fmaxf(s[a],s[b]); s[a]=lo_; s[b]=hi_; }
    CE_(0,1) CE_(2,3) CE_(4,5) CE_(6,7)
    CE_(0,2) CE_(1,3) CE_(4,6) CE_(5,7)
    CE_(1,2) CE_(5,6)
    CE_(0,4) CE_(1,5) CE_(2,6) CE_(3,7)
    CE_(2,4) CE_(3,5)
    CE_(1,2) CE_(3,4) CE_(5,6)
#undef CE_
}

// k (sorted asc) := lowest-8 of union(k, s) where s sorted asc; result sorted.
__device__ __forceinline__ void bmerge8(float k[8], const float s[8]) {
    float t0=fminf(k[0],s[7]), t1=fminf(k[1],s[6]), t2=fminf(k[2],s[5]), t3=fminf(k[3],s[4]);
    float t4=fminf(k[4],s[3]), t5=fminf(k[5],s[2]), t6=fminf(k[6],s[1]), t7=fminf(k[7],s[0]);
    float lo, hi;
    lo=fminf(t0,t4); hi=fmaxf(t0,t4); t0=lo; t4=hi;
    lo=fminf(t1,t5); hi=fmaxf(t1,t5); t1=lo; t5=hi;
    lo=fminf(t2,t6); hi=fmaxf(t2,t6); t2=lo; t6=hi;
    lo=fminf(t3,t7); hi=fmaxf(t3,t7); t3=lo; t7=hi;
    lo=fminf(t0,t2); hi=fmaxf(t0,t2); t0=lo; t2=hi;
    lo=fminf(t1,t3); hi=fmaxf(t1,t3); t1=lo; t3=hi;
    lo=fminf(t4,t6); hi=fmaxf(t4,t6); t4=lo; t6=hi;
    lo=fminf(t5,t7); hi=fmaxf(t5,t7); t5=lo; t7=hi;
    k[0]=fminf(t0,t1); k[1]=fmaxf(t0,t1);
    k[2]=fminf(t2,t3); k[3]=fmaxf(t2,t3);
    k[4]=fminf(t4,t5); k[5]=fmaxf(t4,t5);
    k[6]=fminf(t6,t7); k[7]=fmaxf(t6,t7);
}

__device__ __forceinline__ void wave_merge8(float k[8]) {
    #pragma unroll
    for (int off = 8; off <= 32; off <<= 1) {
        float bb[8];
        #pragma unroll
        for (int i = 0; i < 8; ++i) bb[i] = __shfl_xor(k[i], off, 64);
        bmerge8(k, bb);
    }
}

// ---------------- Kernel 1: FUSED quota + Cholesky + sample ----------------
// f32-filtered rank (exact: monotone double->float rounding + eq-count fallback),
// shfl-based scan (2 barriers instead of 18). All f64 output formulas unchanged.
__global__ __launch_bounds__(512) void fused_kernel(const float* __restrict__ mu_p,
                                                    const float* __restrict__ Sig_p,
                                                    const float* __restrict__ occ,
                                                    const float* __restrict__ mask_parent,
                                                    const float* __restrict__ node_mask,
                                                    const float* __restrict__ z,
                                                    float* __restrict__ out,
                                                    float4* __restrict__ mu4,
                                                    int useF4)
{
    __shared__ double sh_a[K_];                    // pi, then base
    __shared__ double sh_part[32];
    __shared__ alignas(16) double sh_frac[K_];     // exact f64 fracs (fallback path)
    __shared__ alignas(16) float  sh_ffr[K_];      // f32 shadow for the fast rank
    __shared__ float  csf[K_];                     // float cumsum for the search
    __shared__ double Lsh[K_][6];                  // 24 KB Cholesky table
    __shared__ int    sh_wsum[8];
    __shared__ double s_S;
    __shared__ int    s_rem;

    int b  = blockIdx.x >> 3;          // /8
    int rb = blockIdx.x & 7;
    int k  = threadIdx.x;              // 0..511 == parent index

    // ---- quota (np-f64 exact, parallel) ----
    float mk = mask_parent[b * K_ + k];
    bool valid = mk > 0.5f;
    double pi = valid ? (double)occ[b * K_ + k] : 0.0;
    sh_a[k] = pi;
    __syncthreads();

    if (k < 32) {                       // numpy's exact pairwise association
        const double* a = sh_a + (k >> 3) * 128;
        int j = k & 7;
        double r = a[j];
        for (int i = 8; i < 128; i += 8) r += a[j + i];
        sh_part[k] = r;
    }
    __syncthreads();
    if (k == 0) {
        double pw[4];
        #pragma unroll
        for (int blk = 0; blk < 4; ++blk) {
            const double* p = sh_part + blk * 8;
            pw[blk] = ((p[0]+p[1])+(p[2]+p[3]))+((p[4]+p[5])+(p[6]+p[7]));
        }
        s_S = fmax((pw[0]+pw[1])+(pw[2]+pw[3]), 1e-9);
    }
    __syncthreads();

    double raw  = (pi / s_S) * 4096.0;
    double base = floor(raw);
    double frac = valid ? (raw - base) : -1e9;
    sh_frac[k] = frac;
    sh_ffr[k]  = (float)frac;
    __syncthreads();
    sh_a[k] = base;
    __syncthreads();
    if (k < 32) {
        const double* a = sh_a + (k >> 3) * 128;
        int j = k & 7;
        double r = a[j];
        for (int i = 8; i < 128; i += 8) r += a[j + i];
        sh_part[k] = r;
    }
    __syncthreads();
    if (k == 0) {
        double pw[4];
        #pragma unroll
        for (int blk = 0; blk < 4; ++blk) {
            const double* p = sh_part + blk * 8;
            pw[blk] = ((p[0]+p[1])+(p[2]+p[3]))+((p[4]+p[5])+(p[6]+p[7]));
        }
        s_rem = (int)(4096.0 - ((pw[0]+pw[1])+(pw[2]+pw[3])));
    }
    __syncthreads();

    // ---- stable rank in descending frac ----
    // Fast path: f32 compares on float4 LDS reads. Rounding d->f is monotone, so
    // if no OTHER element shares my float value (eq==1, self only), strict float
    // order == strict double order and there are no double-ties. Else: exact f64.
    int nkv = 0;
    if (valid) {
        float fl = (float)frac;
        int rank = 0, eq = 0;
        const float4* f4 = reinterpret_cast<const float4*>(sh_ffr);
        #pragma unroll 4
        for (int j4 = 0; j4 < K_ / 4; ++j4) {
            float4 q = f4[j4];
            rank += (q.x > fl) ? 1 : 0;  eq += (q.x == fl) ? 1 : 0;
            rank += (q.y > fl) ? 1 : 0;  eq += (q.y == fl) ? 1 : 0;
            rank += (q.z > fl) ? 1 : 0;  eq += (q.z == fl) ? 1 : 0;
            rank += (q.w > fl) ? 1 : 0;  eq += (q.w == fl) ? 1 : 0;
        }
        if (__builtin_expect(eq != 1, 0)) {      // float collision: exact f64 rank
            double f = frac;
            rank = 0;
            for (int j = 0; j < K_; ++j) {
                double fj = sh_frac[j];
                rank += ((fj > f) || (fj == f && j < k)) ? 1 : 0;
            }
        }
        nkv = (int)base + (rank < s_rem ? 1 : 0);
    }

    // ---- inclusive scan: wave shfl scan + cross-wave offsets (integer-exact) ----
    {
        int lane = k & 63;
        int w    = k >> 6;
        int v = nkv;
        #pragma unroll
        for (int off = 1; off < 64; off <<= 1) {
            int t = __shfl_up(v, off, 64);
            v += (lane >= off) ? t : 0;
        }
        if (lane == 63) sh_wsum[w] = v;
        __syncthreads();
        int woff = 0;
        #pragma unroll
        for (int i = 0; i < 7; ++i) woff += (i < w) ? sh_wsum[i] : 0;
        csf[k] = (float)(v + woff);
    }

    // ---- per-parent Cholesky into LDS (identical f64 formula) ----
    {
        const float* S = Sig_p + (size_t)(b * K_ + k) * 9;
        double s00 = (double)S[0] + 1e-6;
        double s01 = 0.5 * ((double)S[1] + (double)S[3]);
        double s02 = 0.5 * ((double)S[2] + (double)S[6]);
        double s11 = (double)S[4] + 1e-6;
        double s12 = 0.5 * ((double)S[5] + (double)S[7]);
        double s22 = (double)S[8] + 1e-6;

        const double eps = 1e-6;
        double l00 = sqrt(fmax(s00, eps));
        double l10 = s01 / fmax(l00, eps);
        double l20 = s02 / fmax(l00, eps);
        double l11 = sqrt(fmax(s11 - l10 * l10, eps));
        double l21 = (s12 - l20 * l10) / fmax(l11, eps);
        double l22 = sqrt(fmax(s22 - l20 * l20 - l21 * l21, eps));

        Lsh[k][0] = l00; Lsh[k][1] = l10; Lsh[k][2] = l20;
        Lsh[k][3] = l11; Lsh[k][4] = l21; Lsh[k][5] = l22;
    }
    __syncthreads();   // covers csf + Lsh writes

    // ---- sample node n (LDS binary search + LDS L) ----
    int n = rb * 512 + k;
    float nf = (float)n;
    int lo = 0, hi = K_;
    while (lo < hi) {
        int mid = (lo + hi) >> 1;
        if (csf[mid] <= nf) lo = mid + 1; else hi = mid;
    }
    int p = lo < (K_ - 1) ? lo : (K_ - 1);

    double l00 = Lsh[p][0], l10 = Lsh[p][1], l20 = Lsh[p][2];
    double l11 = Lsh[p][3], l21 = Lsh[p][4], l22 = Lsh[p][5];

    const float* zp = z + (size_t)(b * N_ + n) * (M_ * 3);
    double bestScore = 1e30;
    int pick = 0;
    #pragma unroll
    for (int m = 0; m < M_; ++m) {
        double z0 = (double)zp[m*3+0], z1 = (double)zp[m*3+1], z2 = (double)zp[m*3+2];
        double maha2 = (z0 * z0 + z1 * z1) + z2 * z2;
        double score = (maha2 <= 7.815) ? (double)m : (1e6 + maha2);
        if (score < bestScore) { bestScore = score; pick = m; }
    }

    double z0 = (double)zp[pick*3+0], z1 = (double)zp[pick*3+1], z2 = (double)zp[pick*3+2];
    const float* mu = mu_p + (size_t)(b * K_ + p) * 3;
    double nm = (double)node_mask[b * N_ + n];
    double c0 = ((double)mu[0] + ((l00 * z0)))                       * nm;
    double c1 = ((double)mu[1] + ((l10 * z0 + l11 * z1)))            * nm;
    double c2 = ((double)mu[2] + ((l20 * z0 + l21 * z1) + l22 * z2)) * nm;

    size_t o = (size_t)(b * N_ + n) * 3;
    float f0 = (float)c0, f1 = (float)c1, f2 = (float)c2;
    out[o + 0] = f0;
    out[o + 1] = f1;
    out[o + 2] = f2;
    if (useF4) {
        float sq = (f0 * f0 + f1 * f1) + f2 * f2;
        mu4[b * N_ + n] = make_float4(f0, f1, f2, sq);
    }
    out[(size_t)B_ * N_ * 12 + (size_t)(b * N_ + n)] = (float)p;   // parent_idx output
}

// ---------------- kNN chunk body: 4 rows per thread, batch-8 fill ----------------
template<bool SELF>
__device__ __forceinline__ void do_chunk4(const float4* chk, int seg, int colbase,
                                          const int (&nrow)[RPT],
                                          const float (&a)[RPT][3],
                                          float (&kk)[RPT][8])
{
    #pragma unroll
    for (int g = 0; g < CPL / 8; ++g) {            // 2 batches of 8 columns
        float s[RPT][8];
        #pragma unroll
        for (int u = 0; u < 8; ++u) {
            int j = (g * 8 + u) * SEGS + seg;
            float4 q = chk[j];
            int col = colbase + j;
            #pragma unroll
            for (int r = 0; r < RPT; ++r) {
                // s = sqm - 2*dot ; actual d2 = sqn + s (sqn added post-selection)
                float d = fmaf(a[r][0], q.x, fmaf(a[r][1], q.y, fmaf(a[r][2], q.z, q.w)));
                if (SELF) d = (col == nrow[r]) ? 3.0e38f : d;
                s[r][u] = d;
            }
        }
        #pragma unroll
        for (int r = 0; r < RPT; ++r) { sort8(s[r]); bmerge8(kk[r], s[r]); }
    }
}

// ---------------- Kernel 2: kNN — 512 thr, 32 rows/block ----------------
__global__ __launch_bounds__(KTHREADS, 4) void knn_kernel(const float* __restrict__ Sig_p,
                                                          const float* __restrict__ node_mask,
                                                          const float4* __restrict__ mu4,
                                                          int useF4,
                                                          float* __restrict__ out)
{
    __shared__ float4 chk[CHUNK];                 // 16 KB staged columns (+sq in w)
    __shared__ float  shk[ROWSB][8 * 8 + 1];      // 32 x 65 = 8.3 KB wave partials

    int b   = blockIdx.x / (N_ / ROWSB);          // 128 blocks per batch
    int rb  = blockIdx.x % (N_ / ROWSB);
    int tid = threadIdx.x;
    int slot = tid & (SLOTS - 1);                 // 0..7
    int seg  = tid >> 3;                          // 0..63

    const float* mu0 = out;                       // [B,N,3]

    int   nrow[RPT];
    float a[RPT][3];
    float kk[RPT][8];
    #pragma unroll
    for (int r = 0; r < RPT; ++r) {
        int nn = rb * ROWSB + slot + r * SLOTS;
        nrow[r] = nn;
        float x, y, zv;
        if (useF4) {
            float4 p = mu4[b * N_ + nn]; x = p.x; y = p.y; zv = p.z;
        } else {
            size_t so = (size_t)(b * N_ + nn) * 3;
            x = mu0[so]; y = mu0[so+1]; zv = mu0[so+2];
        }
        a[r][0] = -2.0f * x; a[r][1] = -2.0f * y; a[r][2] = -2.0f * zv;
        #pragma unroll
        for (int i = 0; i < 8; ++i) kk[r][i] = 3.0e38f;
    }

    int selfc = (rb * ROWSB) >> 10;               // chunk containing this block's rows

    for (int c = 0; c < NCHUNK; ++c) {
        __syncthreads();
        if (useF4) {
            for (int j = tid; j < CHUNK; j += KTHREADS)
                chk[j] = mu4[b * N_ + c * CHUNK + j];
        } else {
            for (int j = tid; j < CHUNK; j += KTHREADS) {
                size_t o = (size_t)(b * N_ + c * CHUNK + j) * 3;
                float xx = mu0[o], yy = mu0[o+1], zz = mu0[o+2];
                chk[j] = make_float4(xx, yy, zz, (xx*xx + yy*yy) + zz*zz);
            }
        }
        __syncthreads();

        int colbase = c * CHUNK;
        if (c == selfc)
            do_chunk4<true >(chk, seg, colbase, nrow, a, kk);
        else
            do_chunk4<false>(chk, seg, colbase, nrow, a, kk);
    }

    // in-wave butterfly merge over the 3 seg bits
    #pragma unroll
    for (int r = 0; r < RPT; ++r) wave_merge8(kk[r]);

    int lane = tid & 63;
    int w    = tid >> 6;                          // wave 0..7
    if (lane < SLOTS) {
        #pragma unroll
        for (int r = 0; r < RPT; ++r)
            #pragma unroll
            for (int i = 0; i < 8; ++i)
                shk[lane + r * SLOTS][w * 8 + i] = kk[r][i];
    }
    __syncthreads();

    if (tid < ROWSB) {                             // one lane per row: 8 sorted lists -> 8
        int r = tid;
        int nn = rb * ROWSB + r;
        float best[8];
        #pragma unroll
        for (int i = 0; i < 8; ++i) best[i] = 3.0e38f;
        #pragma unroll
        for (int w2 = 0; w2 < 8; ++w2) {
            float s[8];
            #pragma unroll
            for (int i = 0; i < 8; ++i) s[i] = shk[r][w2 * 8 + i];
            bmerge8(best, s);
        }

        // restore d2 = sqn + s for the selected 8
        float cn;
        if (useF4) {
            cn = mu4[b * N_ + nn].w;
        } else {
            size_t so = (size_t)(b * N_ + nn) * 3;
            float xx = mu0[so], yy = mu0[so+1], zz = mu0[so+2];
            cn = (xx*xx + yy*yy) + zz*zz;
        }

        double s0 = sqrt(fmax((double)(cn + best[0]), 0.0)), s1 = sqrt(fmax((double)(cn + best[1]), 0.0));
        double s2 = sqrt(fmax((double)(cn + best[2]), 0.0)), s3 = sqrt(fmax((double)(cn + best[3]), 0.0));
        double s4 = sqrt(fmax((double)(cn + best[4]), 0.0)), s5 = sqrt(fmax((double)(cn + best[5]), 0.0));
        double s6 = sqrt(fmax((double)(cn + best[6]), 0.0)), s7 = sqrt(fmax((double)(cn + best[7]), 0.0));
        double d_mean = (((s0 + s1) + (s2 + s3)) + ((s4 + s5) + (s6 + s7))) / 8.0;

        double sigma = fmin(fmax(1.5 * d_mean, 1e-3), 100.0);
        double spacing = sigma * sigma + 1e-6;

        int p = (int)out[(size_t)B_ * N_ * 12 + (size_t)(b * N_ + nn)];
        const float* S = Sig_p + (size_t)(b * K_ + p) * 9;
        double s00 = (double)S[0];
        double s01 = 0.5 * ((double)S[1] + (double)S[3]);
        double s02 = 0.5 * ((double)S[2] + (double)S[6]);
        double s11 = (double)S[4];
        double s12 = 0.5 * ((double)S[5] + (double)S[7]);
        double s22 = (double)S[8];

        const double BETA = 0.85;
        const double OMB  = 1.0 - 0.85;
        double nm = (double)node_mask[b * N_ + nn];

        double d00 = (BETA * (s00 + 1e-6) + OMB * spacing) + 1e-6;
        double d11 = (BETA * (s11 + 1e-6) + OMB * spacing) + 1e-6;
        double d22 = (BETA * (s22 + 1e-6) + OMB * spacing) + 1e-6;
        double o01 = BETA * s01;
        double o02 = BETA * s02;
        double o12 = BETA * s12;

        float* Sg = out + (size_t)B_ * N_ * 3 + (size_t)(b * N_ + nn) * 9;
        Sg[0] = (float)(d00 * nm); Sg[1] = (float)(o01 * nm); Sg[2] = (float)(o02 * nm);
        Sg[3] = (float)(o01 * nm); Sg[4] = (float)(d11 * nm); Sg[5] = (float)(o12 * nm);
        Sg[6] = (float)(o02 * nm); Sg[7] = (float)(o12 * nm); Sg[8] = (float)(d22 * nm);
    }
}

// ---------------- launch ----------------
extern "C" void kernel_launch(void* const* d_in, const int* in_sizes, int n_in,
                              void* d_out, int out_size, void* d_ws, size_t ws_size,
                              hipStream_t stream)
{
    const float* mu_p        = (const float*)d_in[0];
    const float* Sig_p       = (const float*)d_in[1];
    const float* occ         = (const float*)d_in[2];
    const float* mask_parent = (const float*)d_in[3];
    const float* node_mask   = (const float*)d_in[4];
    const float* z           = (const float*)d_in[5];
    float* out = (float*)d_out;

    // float4 mu0 copy (with squared norm in .w) lives in d_ws.
    int useF4 = (ws_size >= (size_t)B_ * N_ * sizeof(float4)) ? 1 : 0;
    float4* mu4 = (float4*)d_ws;

    fused_kernel<<<B_ * 8, 512, 0, stream>>>(mu_p, Sig_p, occ, mask_parent,
                                             node_mask, z, out, mu4, useF4);
    knn_kernel<<<B_ * (N_ / ROWSB), KTHREADS, 0, stream>>>(Sig_p, node_mask,
                                                           mu4, useF4, out);
}

// Round 2
// 50.374 us; speedup vs baseline: 1.1334x; 1.0219x over previous
//
#include <hip/hip_runtime.h>
#include <math.h>

#define B_ 4
#define K_ 512
#define N_ 4096
#define M_ 4

#define KTHREADS 512
#define SLOTS 8                 // slot = tid & 7
#define SEGS 64                 // seg  = tid >> 3
#define RPT 4                   // rows per thread: amortizes LDS reads per cand-row
#define ROWSB (SLOTS * RPT)     // 32 rows per block
#define CHUNK 1024
#define NCHUNK (N_ / CHUNK)     // 4
#define CPL (CHUNK / SEGS)      // 16 columns per lane per chunk

// ---------- sorting networks (exact top-8 multiset; lattice min/max only) ----------
__device__ __forceinline__ void sort8(float s[8]) {
#define CE_(a,b) { float lo_=fminf(s[a],s[b]); float hi_=fmaxf(s[a],s[b]); s[a]=lo_; s[b]=hi_; }
    CE_(0,1) CE_(2,3) CE_(4,5) CE_(6,7)
    CE_(0,2) CE_(1,3) CE_(4,6) CE_(5,7)
    CE_(1,2) CE_(5,6)
    CE_(0,4) CE_(1,5) CE_(2,6) CE_(3,7)
    CE_(2,4) CE_(3,5)
    CE_(1,2) CE_(3,4) CE_(5,6)
#undef CE_
}

// k (sorted asc) := lowest-8 of union(k, s) where s sorted asc; result sorted.
__device__ __forceinline__ void bmerge8(float k[8], const float s[8]) {
    float t0=fminf(k[0],s[7]), t1=fminf(k[1],s[6]), t2=fminf(k[2],s[5]), t3=fminf(k[3],s[4]);
    float t4=fminf(k[4],s[3]), t5=fminf(k[5],s[2]), t6=fminf(k[6],s[1]), t7=fminf(k[7],s[0]);
    float lo, hi;
    lo=fminf(t0,t4); hi=fmaxf(t0,t4); t0=lo; t4=hi;
    lo=fminf(t1,t5); hi=fmaxf(t1,t5); t1=lo; t5=hi;
    lo=fminf(t2,t6); hi=fmaxf(t2,t6); t2=lo; t6=hi;
    lo=fminf(t3,t7); hi=fmaxf(t3,t7); t3=lo; t7=hi;
    lo=fminf(t0,t2); hi=fmaxf(t0,t2); t0=lo; t2=hi;
    lo=fminf(t1,t3); hi=fmaxf(t1,t3); t1=lo; t3=hi;
    lo=fminf(t4,t6); hi=fmaxf(t4,t6); t4=lo; t6=hi;
    lo=fminf(t5,t7); hi=fmaxf(t5,t7); t5=lo; t7=hi;
    k[0]=fminf(t0,t1); k[1]=fmaxf(t0,t1);
    k[2]=fminf(t2,t3); k[3]=fmaxf(t2,t3);
    k[4]=fminf(t4,t5); k[5]=fmaxf(t4,t5);
    k[6]=fminf(t6,t7); k[7]=fmaxf(t6,t7);
}

__device__ __forceinline__ void wave_merge8(float k[8]) {
    #pragma unroll
    for (int off = 8; off <= 32; off <<= 1) {
        float bb[8];
        #pragma unroll
        for (int i = 0; i < 8; ++i) bb[i] = __shfl_xor(k[i], off, 64);
        bmerge8(k, bb);
    }
}

// ---------------- Kernel 1: FUSED quota + Cholesky + sample ----------------
// f32-filtered rank (exact: monotone double->float rounding + eq-count fallback),
// shfl-based scan (2 barriers instead of 18). All f64 output formulas unchanged.
__global__ __launch_bounds__(512) void fused_kernel(const float* __restrict__ mu_p,
                                                    const float* __restrict__ Sig_p,
                                                    const float* __restrict__ occ,
                                                    const float* __restrict__ mask_parent,
                                                    const float* __restrict__ node_mask,
                                                    const float* __restrict__ z,
                                                    float* __restrict__ out,
                                                    float4* __restrict__ mu4,
                                                    int useF4)
{
    __shared__ double sh_a[K_];                    // pi, then base
    __shared__ double sh_part[32];
    __shared__ alignas(16) double sh_frac[K_];     // exact f64 fracs (fallback path)
    __shared__ alignas(16) float  sh_ffr[K_];      // f32 shadow for the fast rank
    __shared__ float  csf[K_];                     // float cumsum for the search
    __shared__ double Lsh[K_][6];                  // 24 KB Cholesky table
    __shared__ int    sh_wsum[8];
    __shared__ double s_S;
    __shared__ int    s_rem;

    int b  = blockIdx.x >> 3;          // /8
    int rb = blockIdx.x & 7;
    int k  = threadIdx.x;              // 0..511 == parent index

    // ---- quota (np-f64 exact, parallel) ----
    float mk = mask_parent[b * K_ + k];
    bool valid = mk > 0.5f;
    double pi = valid ? (double)occ[b * K_ + k] : 0.0;
    sh_a[k] = pi;
    __syncthreads();

    if (k < 32) {                       // numpy's exact pairwise association
        const double* a = sh_a + (k >> 3) * 128;
        int j = k & 7;
        double r = a[j];
        for (int i = 8; i < 128; i += 8) r += a[j + i];
        sh_part[k] = r;
    }
    __syncthreads();
    if (k == 0) {
        double pw[4];
        #pragma unroll
        for (int blk = 0; blk < 4; ++blk) {
            const double* p = sh_part + blk * 8;
            pw[blk] = ((p[0]+p[1])+(p[2]+p[3]))+((p[4]+p[5])+(p[6]+p[7]));
        }
        s_S = fmax((pw[0]+pw[1])+(pw[2]+pw[3]), 1e-9);
    }
    __syncthreads();

    double raw  = (pi / s_S) * 4096.0;
    double base = floor(raw);
    double frac = valid ? (raw - base) : -1e9;
    sh_frac[k] = frac;
    sh_ffr[k]  = (float)frac;
    __syncthreads();
    sh_a[k] = base;
    __syncthreads();
    if (k < 32) {
        const double* a = sh_a + (k >> 3) * 128;
        int j = k & 7;
        double r = a[j];
        for (int i = 8; i < 128; i += 8) r += a[j + i];
        sh_part[k] = r;
    }
    __syncthreads();
    if (k == 0) {
        double pw[4];
        #pragma unroll
        for (int blk = 0; blk < 4; ++blk) {
            const double* p = sh_part + blk * 8;
            pw[blk] = ((p[0]+p[1])+(p[2]+p[3]))+((p[4]+p[5])+(p[6]+p[7]));
        }
        s_rem = (int)(4096.0 - ((pw[0]+pw[1])+(pw[2]+pw[3])));
    }
    __syncthreads();

    // ---- stable rank in descending frac ----
    // Fast path: f32 compares on float4 LDS reads. Rounding d->f is monotone, so
    // if no OTHER element shares my float value (eq==1, self only), strict float
    // order == strict double order and there are no double-ties. Else: exact f64.
    int nkv = 0;
    if (valid) {
        float fl = (float)frac;
        int rank = 0, eq = 0;
        const float4* f4 = reinterpret_cast<const float4*>(sh_ffr);
        #pragma unroll 4
        for (int j4 = 0; j4 < K_ / 4; ++j4) {
            float4 q = f4[j4];
            rank += (q.x > fl) ? 1 : 0;  eq += (q.x == fl) ? 1 : 0;
            rank += (q.y > fl) ? 1 : 0;  eq += (q.y == fl) ? 1 : 0;
            rank += (q.z > fl) ? 1 : 0;  eq += (q.z == fl) ? 1 : 0;
            rank += (q.w > fl) ? 1 : 0;  eq += (q.w == fl) ? 1 : 0;
        }
        if (__builtin_expect(eq != 1, 0)) {      // float collision: exact f64 rank
            double f = frac;
            rank = 0;
            for (int j = 0; j < K_; ++j) {
                double fj = sh_frac[j];
                rank += ((fj > f) || (fj == f && j < k)) ? 1 : 0;
            }
        }
        nkv = (int)base + (rank < s_rem ? 1 : 0);
    }

    // ---- inclusive scan: wave shfl scan + cross-wave offsets (integer-exact) ----
    {
        int lane = k & 63;
        int w    = k >> 6;
        int v = nkv;
        #pragma unroll
        for (int off = 1; off < 64; off <<= 1) {
            int t = __shfl_up(v, off, 64);
            v += (lane >= off) ? t : 0;
        }
        if (lane == 63) sh_wsum[w] = v;
        __syncthreads();
        int woff = 0;
        #pragma unroll
        for (int i = 0; i < 7; ++i) woff += (i < w) ? sh_wsum[i] : 0;
        csf[k] = (float)(v + woff);
    }

    // ---- per-parent Cholesky into LDS (identical f64 formula) ----
    {
        const float* S = Sig_p + (size_t)(b * K_ + k) * 9;
        double s00 = (double)S[0] + 1e-6;
        double s01 = 0.5 * ((double)S[1] + (double)S[3]);
        double s02 = 0.5 * ((double)S[2] + (double)S[6]);
        double s11 = (double)S[4] + 1e-6;
        double s12 = 0.5 * ((double)S[5] + (double)S[7]);
        double s22 = (double)S[8] + 1e-6;

        const double eps = 1e-6;
        double l00 = sqrt(fmax(s00, eps));
        double l10 = s01 / fmax(l00, eps);
        double l20 = s02 / fmax(l00, eps);
        double l11 = sqrt(fmax(s11 - l10 * l10, eps));
        double l21 = (s12 - l20 * l10) / fmax(l11, eps);
        double l22 = sqrt(fmax(s22 - l20 * l20 - l21 * l21, eps));

        Lsh[k][0] = l00; Lsh[k][1] = l10; Lsh[k][2] = l20;
        Lsh[k][3] = l11; Lsh[k][4] = l21; Lsh[k][5] = l22;
    }
    __syncthreads();   // covers csf + Lsh writes

    // ---- sample node n (LDS binary search + LDS L) ----
    int n = rb * 512 + k;
    float nf = (float)n;
    int lo = 0, hi = K_;
    while (lo < hi) {
        int mid = (lo + hi) >> 1;
        if (csf[mid] <= nf) lo = mid + 1; else hi = mid;
    }
    int p = lo < (K_ - 1) ? lo : (K_ - 1);

    double l00 = Lsh[p][0], l10 = Lsh[p][1], l20 = Lsh[p][2];
    double l11 = Lsh[p][3], l21 = Lsh[p][4], l22 = Lsh[p][5];

    const float* zp = z + (size_t)(b * N_ + n) * (M_ * 3);
    double bestScore = 1e30;
    int pick = 0;
    #pragma unroll
    for (int m = 0; m < M_; ++m) {
        double z0 = (double)zp[m*3+0], z1 = (double)zp[m*3+1], z2 = (double)zp[m*3+2];
        double maha2 = (z0 * z0 + z1 * z1) + z2 * z2;
        double score = (maha2 <= 7.815) ? (double)m : (1e6 + maha2);
        if (score < bestScore) { bestScore = score; pick = m; }
    }

    double z0 = (double)zp[pick*3+0], z1 = (double)zp[pick*3+1], z2 = (double)zp[pick*3+2];
    const float* mu = mu_p + (size_t)(b * K_ + p) * 3;
    double nm = (double)node_mask[b * N_ + n];
    double c0 = ((double)mu[0] + ((l00 * z0)))                       * nm;
    double c1 = ((double)mu[1] + ((l10 * z0 + l11 * z1)))            * nm;
    double c2 = ((double)mu[2] + ((l20 * z0 + l21 * z1) + l22 * z2)) * nm;

    size_t o = (size_t)(b * N_ + n) * 3;
    float f0 = (float)c0, f1 = (float)c1, f2 = (float)c2;
    out[o + 0] = f0;
    out[o + 1] = f1;
    out[o + 2] = f2;
    if (useF4) {
        float sq = (f0 * f0 + f1 * f1) + f2 * f2;
        mu4[b * N_ + n] = make_float4(f0, f1, f2, sq);
    }
    out[(size_t)B_ * N_ * 12 + (size_t)(b * N_ + n)] = (float)p;   // parent_idx output
}

// ---------------- kNN chunk body: 4 rows per thread, batch-8 fill ----------------
template<bool SELF>
__device__ __forceinline__ void do_chunk4(const float4* chk, int seg, int colbase,
                                          const int (&nrow)[RPT],
                                          const float (&a)[RPT][3],
                                          float (&kk)[RPT][8])
{
    #pragma unroll
    for (int g = 0; g < CPL / 8; ++g) {            // 2 batches of 8 columns
        float s[RPT][8];
        #pragma unroll
        for (int u = 0; u < 8; ++u) {
            int j = (g * 8 + u) * SEGS + seg;
            float4 q = chk[j];
            int col = colbase + j;
            #pragma unroll
            for (int r = 0; r < RPT; ++r) {
                // s = sqm - 2*dot ; actual d2 = sqn + s (sqn added post-selection)
                float d = fmaf(a[r][0], q.x, fmaf(a[r][1], q.y, fmaf(a[r][2], q.z, q.w)));
                if (SELF) d = (col == nrow[r]) ? 3.0e38f : d;
                s[r][u] = d;
            }
        }
        #pragma unroll
        for (int r = 0; r < RPT; ++r) { sort8(s[r]); bmerge8(kk[r], s[r]); }
    }
}

// ---------------- Kernel 2: kNN — 512 thr, 32 rows/block ----------------
// amdgpu_waves_per_eu(4,4) pins the allocator at the 128-VGPR tier (16 waves/CU,
// 2 blocks/CU): the R1 build targeted 8 waves/EU (64 VGPR) and spilled ~10 MB to
// scratch (WRITE_SIZE 10.8 MB vs 0.6 MB of real output).
__global__ __launch_bounds__(KTHREADS)
__attribute__((amdgpu_waves_per_eu(4, 4)))
void knn_kernel(const float* __restrict__ Sig_p,
                const float* __restrict__ node_mask,
                const float4* __restrict__ mu4,
                int useF4,
                float* __restrict__ out)
{
    __shared__ float4 chk[CHUNK];                 // 16 KB staged columns (+sq in w)
    __shared__ float  shk[ROWSB][8 * 8 + 1];      // 32 x 65 = 8.3 KB wave partials

    int b   = blockIdx.x / (N_ / ROWSB);          // 128 blocks per batch
    int rb  = blockIdx.x % (N_ / ROWSB);
    int tid = threadIdx.x;
    int slot = tid & (SLOTS - 1);                 // 0..7
    int seg  = tid >> 3;                          // 0..63

    const float* mu0 = out;                       // [B,N,3]

    int   nrow[RPT];
    float a[RPT][3];
    float kk[RPT][8];
    #pragma unroll
    for (int r = 0; r < RPT; ++r) {
        int nn = rb * ROWSB + slot + r * SLOTS;
        nrow[r] = nn;
        float x, y, zv;
        if (useF4) {
            float4 p = mu4[b * N_ + nn]; x = p.x; y = p.y; zv = p.z;
        } else {
            size_t so = (size_t)(b * N_ + nn) * 3;
            x = mu0[so]; y = mu0[so+1]; zv = mu0[so+2];
        }
        a[r][0] = -2.0f * x; a[r][1] = -2.0f * y; a[r][2] = -2.0f * zv;
        #pragma unroll
        for (int i = 0; i < 8; ++i) kk[r][i] = 3.0e38f;
    }

    int selfc = (rb * ROWSB) >> 10;               // chunk containing this block's rows

    for (int c = 0; c < NCHUNK; ++c) {
        __syncthreads();
        if (useF4) {
            for (int j = tid; j < CHUNK; j += KTHREADS)
                chk[j] = mu4[b * N_ + c * CHUNK + j];
        } else {
            for (int j = tid; j < CHUNK; j += KTHREADS) {
                size_t o = (size_t)(b * N_ + c * CHUNK + j) * 3;
                float xx = mu0[o], yy = mu0[o+1], zz = mu0[o+2];
                chk[j] = make_float4(xx, yy, zz, (xx*xx + yy*yy) + zz*zz);
            }
        }
        __syncthreads();

        int colbase = c * CHUNK;
        if (c == selfc)
            do_chunk4<true >(chk, seg, colbase, nrow, a, kk);
        else
            do_chunk4<false>(chk, seg, colbase, nrow, a, kk);
    }

    // in-wave butterfly merge over the 3 seg bits
    #pragma unroll
    for (int r = 0; r < RPT; ++r) wave_merge8(kk[r]);

    int lane = tid & 63;
    int w    = tid >> 6;                          // wave 0..7
    if (lane < SLOTS) {
        #pragma unroll
        for (int r = 0; r < RPT; ++r)
            #pragma unroll
            for (int i = 0; i < 8; ++i)
                shk[lane + r * SLOTS][w * 8 + i] = kk[r][i];
    }
    __syncthreads();

    if (tid < ROWSB) {                             // one lane per row: 8 sorted lists -> 8
        int r = tid;
        int nn = rb * ROWSB + r;
        float best[8];
        #pragma unroll
        for (int i = 0; i < 8; ++i) best[i] = 3.0e38f;
        #pragma unroll
        for (int w2 = 0; w2 < 8; ++w2) {
            float s[8];
            #pragma unroll
            for (int i = 0; i < 8; ++i) s[i] = shk[r][w2 * 8 + i];
            bmerge8(best, s);
        }

        // restore d2 = sqn + s for the selected 8
        float cn;
        if (useF4) {
            cn = mu4[b * N_ + nn].w;
        } else {
            size_t so = (size_t)(b * N_ + nn) * 3;
            float xx = mu0[so], yy = mu0[so+1], zz = mu0[so+2];
            cn = (xx*xx + yy*yy) + zz*zz;
        }

        double s0 = sqrt(fmax((double)(cn + best[0]), 0.0)), s1 = sqrt(fmax((double)(cn + best[1]), 0.0));
        double s2 = sqrt(fmax((double)(cn + best[2]), 0.0)), s3 = sqrt(fmax((double)(cn + best[3]), 0.0));
        double s4 = sqrt(fmax((double)(cn + best[4]), 0.0)), s5 = sqrt(fmax((double)(cn + best[5]), 0.0));
        double s6 = sqrt(fmax((double)(cn + best[6]), 0.0)), s7 = sqrt(fmax((double)(cn + best[7]), 0.0));
        double d_mean = (((s0 + s1) + (s2 + s3)) + ((s4 + s5) + (s6 + s7))) / 8.0;

        double sigma = fmin(fmax(1.5 * d_mean, 1e-3), 100.0);
        double spacing = sigma * sigma + 1e-6;

        int p = (int)out[(size_t)B_ * N_ * 12 + (size_t)(b * N_ + nn)];
        const float* S = Sig_p + (size_t)(b * K_ + p) * 9;
        double s00 = (double)S[0];
        double s01 = 0.5 * ((double)S[1] + (double)S[3]);
        double s02 = 0.5 * ((double)S[2] + (double)S[6]);
        double s11 = (double)S[4];
        double s12 = 0.5 * ((double)S[5] + (double)S[7]);
        double s22 = (double)S[8];

        const double BETA = 0.85;
        const double OMB  = 1.0 - 0.85;
        double nm = (double)node_mask[b * N_ + nn];

        double d00 = (BETA * (s00 + 1e-6) + OMB * spacing) + 1e-6;
        double d11 = (BETA * (s11 + 1e-6) + OMB * spacing) + 1e-6;
        double d22 = (BETA * (s22 + 1e-6) + OMB * spacing) + 1e-6;
        double o01 = BETA * s01;
        double o02 = BETA * s02;
        double o12 = BETA * s12;

        float* Sg = out + (size_t)B_ * N_ * 3 + (size_t)(b * N_ + nn) * 9;
        Sg[0] = (float)(d00 * nm); Sg[1] = (float)(o01 * nm); Sg[2] = (float)(o02 * nm);
        Sg[3] = (float)(o01 * nm); Sg[4] = (float)(d11 * nm); Sg[5] = (float)(o12 * nm);
        Sg[6] = (float)(o02 * nm); Sg[7] = (float)(o12 * nm); Sg[8] = (float)(d22 * nm);
    }
}

// ---------------- launch ----------------
extern "C" void kernel_launch(void* const* d_in, const int* in_sizes, int n_in,
                              void* d_out, int out_size, void* d_ws, size_t ws_size,
                              hipStream_t stream)
{
    const float* mu_p        = (const float*)d_in[0];
    const float* Sig_p       = (const float*)d_in[1];
    const float* occ         = (const float*)d_in[2];
    const float* mask_parent = (const float*)d_in[3];
    const float* node_mask   = (const float*)d_in[4];
    const float* z           = (const float*)d_in[5];
    float* out = (float*)d_out;

    // float4 mu0 copy (with squared norm in .w) lives in d_ws.
    int useF4 = (ws_size >= (size_t)B_ * N_ * sizeof(float4)) ? 1 : 0;
    float4* mu4 = (float4*)d_ws;

    fused_kernel<<<B_ * 8, 512, 0, stream>>>(mu_p, Sig_p, occ, mask_parent,
                                             node_mask, z, out, mu4, useF4);
    knn_kernel<<<B_ * (N_ / ROWSB), KTHREADS, 0, stream>>>(Sig_p, node_mask,
                                                           mu4, useF4, out);
}

// Round 3
// 49.816 us; speedup vs baseline: 1.1461x; 1.0112x over previous
//
#include <hip/hip_runtime.h>
#include <math.h>

#define B_ 4
#define K_ 512
#define N_ 4096
#define M_ 4

#define KTHREADS 512
#define SLOTS 8                 // slot = tid & 7
#define SEGS 64                 // seg  = tid >> 3
#define RPT 4                   // rows per thread (named-register form; no arrays-of-arrays)
#define ROWSB (SLOTS * RPT)     // 32 rows per block
#define CHUNK 1024
#define NCHUNK (N_ / CHUNK)     // 4
#define CPL (CHUNK / SEGS)      // 16 columns per lane per chunk

// ---------- sorting networks (exact top-8 multiset; lattice min/max only) ----------
__device__ __forceinline__ void sort8(float s[8]) {
#define CE_(a,b) { float lo_=fminf(s[a],s[b]); float hi_=fmaxf(s[a],s[b]); s[a]=lo_; s[b]=hi_; }
    CE_(0,1) CE_(2,3) CE_(4,5) CE_(6,7)
    CE_(0,2) CE_(1,3) CE_(4,6) CE_(5,7)
    CE_(1,2) CE_(5,6)
    CE_(0,4) CE_(1,5) CE_(2,6) CE_(3,7)
    CE_(2,4) CE_(3,5)
    CE_(1,2) CE_(3,4) CE_(5,6)
#undef CE_
}

// k (sorted asc) := lowest-8 of union(k, s) where s sorted asc; result sorted.
__device__ __forceinline__ void bmerge8(float k[8], const float s[8]) {
    float t0=fminf(k[0],s[7]), t1=fminf(k[1],s[6]), t2=fminf(k[2],s[5]), t3=fminf(k[3],s[4]);
    float t4=fminf(k[4],s[3]), t5=fminf(k[5],s[2]), t6=fminf(k[6],s[1]), t7=fminf(k[7],s[0]);
    float lo, hi;
    lo=fminf(t0,t4); hi=fmaxf(t0,t4); t0=lo; t4=hi;
    lo=fminf(t1,t5); hi=fmaxf(t1,t5); t1=lo; t5=hi;
    lo=fminf(t2,t6); hi=fmaxf(t2,t6); t2=lo; t6=hi;
    lo=fminf(t3,t7); hi=fmaxf(t3,t7); t3=lo; t7=hi;
    lo=fminf(t0,t2); hi=fmaxf(t0,t2); t0=lo; t2=hi;
    lo=fminf(t1,t3); hi=fmaxf(t1,t3); t1=lo; t3=hi;
    lo=fminf(t4,t6); hi=fmaxf(t4,t6); t4=lo; t6=hi;
    lo=fminf(t5,t7); hi=fmaxf(t5,t7); t5=lo; t7=hi;
    k[0]=fminf(t0,t1); k[1]=fmaxf(t0,t1);
    k[2]=fminf(t2,t3); k[3]=fmaxf(t2,t3);
    k[4]=fminf(t4,t5); k[5]=fmaxf(t4,t5);
    k[6]=fminf(t6,t7); k[7]=fmaxf(t6,t7);
}

__device__ __forceinline__ void wave_merge8(float k[8]) {
    #pragma unroll
    for (int off = 8; off <= 32; off <<= 1) {
        float bb[8];
        #pragma unroll
        for (int i = 0; i < 8; ++i) bb[i] = __shfl_xor(k[i], off, 64);
        bmerge8(k, bb);
    }
}

// ---------------- Kernel 1: FUSED quota + Cholesky + sample ----------------
// (unchanged from R2 — passing, absmax 0.0078)
__global__ __launch_bounds__(512) void fused_kernel(const float* __restrict__ mu_p,
                                                    const float* __restrict__ Sig_p,
                                                    const float* __restrict__ occ,
                                                    const float* __restrict__ mask_parent,
                                                    const float* __restrict__ node_mask,
                                                    const float* __restrict__ z,
                                                    float* __restrict__ out,
                                                    float4* __restrict__ mu4,
                                                    int useF4)
{
    __shared__ double sh_a[K_];                    // pi, then base
    __shared__ double sh_part[32];
    __shared__ alignas(16) double sh_frac[K_];     // exact f64 fracs (fallback path)
    __shared__ alignas(16) float  sh_ffr[K_];      // f32 shadow for the fast rank
    __shared__ float  csf[K_];                     // float cumsum for the search
    __shared__ double Lsh[K_][6];                  // 24 KB Cholesky table
    __shared__ int    sh_wsum[8];
    __shared__ double s_S;
    __shared__ int    s_rem;

    int b  = blockIdx.x >> 3;          // /8
    int rb = blockIdx.x & 7;
    int k  = threadIdx.x;              // 0..511 == parent index

    // ---- quota (np-f64 exact, parallel) ----
    float mk = mask_parent[b * K_ + k];
    bool valid = mk > 0.5f;
    double pi = valid ? (double)occ[b * K_ + k] : 0.0;
    sh_a[k] = pi;
    __syncthreads();

    if (k < 32) {                       // numpy's exact pairwise association
        const double* a = sh_a + (k >> 3) * 128;
        int j = k & 7;
        double r = a[j];
        for (int i = 8; i < 128; i += 8) r += a[j + i];
        sh_part[k] = r;
    }
    __syncthreads();
    if (k == 0) {
        double pw[4];
        #pragma unroll
        for (int blk = 0; blk < 4; ++blk) {
            const double* p = sh_part + blk * 8;
            pw[blk] = ((p[0]+p[1])+(p[2]+p[3]))+((p[4]+p[5])+(p[6]+p[7]));
        }
        s_S = fmax((pw[0]+pw[1])+(pw[2]+pw[3]), 1e-9);
    }
    __syncthreads();

    double raw  = (pi / s_S) * 4096.0;
    double base = floor(raw);
    double frac = valid ? (raw - base) : -1e9;
    sh_frac[k] = frac;
    sh_ffr[k]  = (float)frac;
    __syncthreads();
    sh_a[k] = base;
    __syncthreads();
    if (k < 32) {
        const double* a = sh_a + (k >> 3) * 128;
        int j = k & 7;
        double r = a[j];
        for (int i = 8; i < 128; i += 8) r += a[j + i];
        sh_part[k] = r;
    }
    __syncthreads();
    if (k == 0) {
        double pw[4];
        #pragma unroll
        for (int blk = 0; blk < 4; ++blk) {
            const double* p = sh_part + blk * 8;
            pw[blk] = ((p[0]+p[1])+(p[2]+p[3]))+((p[4]+p[5])+(p[6]+p[7]));
        }
        s_rem = (int)(4096.0 - ((pw[0]+pw[1])+(pw[2]+pw[3])));
    }
    __syncthreads();

    // ---- stable rank in descending frac ----
    int nkv = 0;
    if (valid) {
        float fl = (float)frac;
        int rank = 0, eq = 0;
        const float4* f4 = reinterpret_cast<const float4*>(sh_ffr);
        #pragma unroll 4
        for (int j4 = 0; j4 < K_ / 4; ++j4) {
            float4 q = f4[j4];
            rank += (q.x > fl) ? 1 : 0;  eq += (q.x == fl) ? 1 : 0;
            rank += (q.y > fl) ? 1 : 0;  eq += (q.y == fl) ? 1 : 0;
            rank += (q.z > fl) ? 1 : 0;  eq += (q.z == fl) ? 1 : 0;
            rank += (q.w > fl) ? 1 : 0;  eq += (q.w == fl) ? 1 : 0;
        }
        if (__builtin_expect(eq != 1, 0)) {      // float collision: exact f64 rank
            double f = frac;
            rank = 0;
            for (int j = 0; j < K_; ++j) {
                double fj = sh_frac[j];
                rank += ((fj > f) || (fj == f && j < k)) ? 1 : 0;
            }
        }
        nkv = (int)base + (rank < s_rem ? 1 : 0);
    }

    // ---- inclusive scan: wave shfl scan + cross-wave offsets (integer-exact) ----
    {
        int lane = k & 63;
        int w    = k >> 6;
        int v = nkv;
        #pragma unroll
        for (int off = 1; off < 64; off <<= 1) {
            int t = __shfl_up(v, off, 64);
            v += (lane >= off) ? t : 0;
        }
        if (lane == 63) sh_wsum[w] = v;
        __syncthreads();
        int woff = 0;
        #pragma unroll
        for (int i = 0; i < 7; ++i) woff += (i < w) ? sh_wsum[i] : 0;
        csf[k] = (float)(v + woff);
    }

    // ---- per-parent Cholesky into LDS (identical f64 formula) ----
    {
        const float* S = Sig_p + (size_t)(b * K_ + k) * 9;
        double s00 = (double)S[0] + 1e-6;
        double s01 = 0.5 * ((double)S[1] + (double)S[3]);
        double s02 = 0.5 * ((double)S[2] + (double)S[6]);
        double s11 = (double)S[4] + 1e-6;
        double s12 = 0.5 * ((double)S[5] + (double)S[7]);
        double s22 = (double)S[8] + 1e-6;

        const double eps = 1e-6;
        double l00 = sqrt(fmax(s00, eps));
        double l10 = s01 / fmax(l00, eps);
        double l20 = s02 / fmax(l00, eps);
        double l11 = sqrt(fmax(s11 - l10 * l10, eps));
        double l21 = (s12 - l20 * l10) / fmax(l11, eps);
        double l22 = sqrt(fmax(s22 - l20 * l20 - l21 * l21, eps));

        Lsh[k][0] = l00; Lsh[k][1] = l10; Lsh[k][2] = l20;
        Lsh[k][3] = l11; Lsh[k][4] = l21; Lsh[k][5] = l22;
    }
    __syncthreads();   // covers csf + Lsh writes

    // ---- sample node n (LDS binary search + LDS L) ----
    int n = rb * 512 + k;
    float nf = (float)n;
    int lo = 0, hi = K_;
    while (lo < hi) {
        int mid = (lo + hi) >> 1;
        if (csf[mid] <= nf) lo = mid + 1; else hi = mid;
    }
    int p = lo < (K_ - 1) ? lo : (K_ - 1);

    double l00 = Lsh[p][0], l10 = Lsh[p][1], l20 = Lsh[p][2];
    double l11 = Lsh[p][3], l21 = Lsh[p][4], l22 = Lsh[p][5];

    const float* zp = z + (size_t)(b * N_ + n) * (M_ * 3);
    double bestScore = 1e30;
    int pick = 0;
    #pragma unroll
    for (int m = 0; m < M_; ++m) {
        double z0 = (double)zp[m*3+0], z1 = (double)zp[m*3+1], z2 = (double)zp[m*3+2];
        double maha2 = (z0 * z0 + z1 * z1) + z2 * z2;
        double score = (maha2 <= 7.815) ? (double)m : (1e6 + maha2);
        if (score < bestScore) { bestScore = score; pick = m; }
    }

    double z0 = (double)zp[pick*3+0], z1 = (double)zp[pick*3+1], z2 = (double)zp[pick*3+2];
    const float* mu = mu_p + (size_t)(b * K_ + p) * 3;
    double nm = (double)node_mask[b * N_ + n];
    double c0 = ((double)mu[0] + ((l00 * z0)))                       * nm;
    double c1 = ((double)mu[1] + ((l10 * z0 + l11 * z1)))            * nm;
    double c2 = ((double)mu[2] + ((l20 * z0 + l21 * z1) + l22 * z2)) * nm;

    size_t o = (size_t)(b * N_ + n) * 3;
    float f0 = (float)c0, f1 = (float)c1, f2 = (float)c2;
    out[o + 0] = f0;
    out[o + 1] = f1;
    out[o + 2] = f2;
    if (useF4) {
        float sq = (f0 * f0 + f1 * f1) + f2 * f2;
        mu4[b * N_ + n] = make_float4(f0, f1, f2, sq);
    }
    out[(size_t)B_ * N_ * 12 + (size_t)(b * N_ + n)] = (float)p;   // parent_idx output
}

// ---------------- kNN chunk body: 4 rows per thread, fully NAMED registers ----------------
// R1/R2 regression root-cause: 2-D arrays (s[RPT][8]) indexed via loop vars defeated
// SROA -> arrays lowered to scratch (VGPR=64, ~10 MB HBM spill traffic). This form
// keeps every value in a named register with compile-time-constant indices only.
template<bool SELF>
__device__ __forceinline__ void do_chunk4(const float4* chk, int seg, int colbase,
                                          int n0, int n1, int n2, int n3,
                                          float a00, float a01, float a02,
                                          float a10, float a11, float a12,
                                          float a20, float a21, float a22,
                                          float a30, float a31, float a32,
                                          float k0[8], float k1[8],
                                          float k2[8], float k3[8])
{
    #pragma unroll
    for (int g = 0; g < CPL / 8; ++g) {            // 2 batches of 8 columns
        float s0[8], s1[8], s2[8], s3[8];
        #pragma unroll
        for (int u = 0; u < 8; ++u) {
            int j = (g * 8 + u) * SEGS + seg;
            float4 q = chk[j];
            // s = sqm - 2*dot ; actual d2 = sqn + s (sqn added post-selection)
            float d0 = fmaf(a00, q.x, fmaf(a01, q.y, fmaf(a02, q.z, q.w)));
            float d1 = fmaf(a10, q.x, fmaf(a11, q.y, fmaf(a12, q.z, q.w)));
            float d2 = fmaf(a20, q.x, fmaf(a21, q.y, fmaf(a22, q.z, q.w)));
            float d3 = fmaf(a30, q.x, fmaf(a31, q.y, fmaf(a32, q.z, q.w)));
            if (SELF) {
                int col = colbase + j;
                d0 = (col == n0) ? 3.0e38f : d0;
                d1 = (col == n1) ? 3.0e38f : d1;
                d2 = (col == n2) ? 3.0e38f : d2;
                d3 = (col == n3) ? 3.0e38f : d3;
            }
            s0[u] = d0; s1[u] = d1; s2[u] = d2; s3[u] = d3;
        }
        sort8(s0); bmerge8(k0, s0);
        sort8(s1); bmerge8(k1, s1);
        sort8(s2); bmerge8(k2, s2);
        sort8(s3); bmerge8(k3, s3);
    }
}

// ---------------- Kernel 2: kNN — 512 thr, 32 rows/block ----------------
__global__ __launch_bounds__(KTHREADS, 4) void knn_kernel(const float* __restrict__ Sig_p,
                                                          const float* __restrict__ node_mask,
                                                          const float4* __restrict__ mu4,
                                                          int useF4,
                                                          float* __restrict__ out)
{
    __shared__ float4 chk[CHUNK];                 // 16 KB staged columns (+sq in w)
    __shared__ float  shk[ROWSB][8 * 8 + 1];      // 32 x 65 = 8.3 KB wave partials

    int b   = blockIdx.x / (N_ / ROWSB);          // 128 blocks per batch
    int rb  = blockIdx.x % (N_ / ROWSB);
    int tid = threadIdx.x;
    int slot = tid & (SLOTS - 1);                 // 0..7
    int seg  = tid >> 3;                          // 0..63

    const float* mu0 = out;                       // [B,N,3]

    int n0 = rb * ROWSB + slot;
    int n1 = n0 + SLOTS;
    int n2 = n0 + 2 * SLOTS;
    int n3 = n0 + 3 * SLOTS;

    float a00, a01, a02, a10, a11, a12, a20, a21, a22, a30, a31, a32;
    {
        float x, y, zv;
        if (useF4) { float4 p = mu4[b * N_ + n0]; x = p.x; y = p.y; zv = p.z; }
        else { size_t so = (size_t)(b * N_ + n0) * 3; x = mu0[so]; y = mu0[so+1]; zv = mu0[so+2]; }
        a00 = -2.0f * x; a01 = -2.0f * y; a02 = -2.0f * zv;
        if (useF4) { float4 p = mu4[b * N_ + n1]; x = p.x; y = p.y; zv = p.z; }
        else { size_t so = (size_t)(b * N_ + n1) * 3; x = mu0[so]; y = mu0[so+1]; zv = mu0[so+2]; }
        a10 = -2.0f * x; a11 = -2.0f * y; a12 = -2.0f * zv;
        if (useF4) { float4 p = mu4[b * N_ + n2]; x = p.x; y = p.y; zv = p.z; }
        else { size_t so = (size_t)(b * N_ + n2) * 3; x = mu0[so]; y = mu0[so+1]; zv = mu0[so+2]; }
        a20 = -2.0f * x; a21 = -2.0f * y; a22 = -2.0f * zv;
        if (useF4) { float4 p = mu4[b * N_ + n3]; x = p.x; y = p.y; zv = p.z; }
        else { size_t so = (size_t)(b * N_ + n3) * 3; x = mu0[so]; y = mu0[so+1]; zv = mu0[so+2]; }
        a30 = -2.0f * x; a31 = -2.0f * y; a32 = -2.0f * zv;
    }

    float k0[8], k1[8], k2[8], k3[8];
    #pragma unroll
    for (int i = 0; i < 8; ++i) { k0[i] = 3.0e38f; k1[i] = 3.0e38f; k2[i] = 3.0e38f; k3[i] = 3.0e38f; }

    int selfc = (rb * ROWSB) >> 10;               // chunk containing this block's rows

    for (int c = 0; c < NCHUNK; ++c) {
        __syncthreads();
        if (useF4) {
            for (int j = tid; j < CHUNK; j += KTHREADS)
                chk[j] = mu4[b * N_ + c * CHUNK + j];
        } else {
            for (int j = tid; j < CHUNK; j += KTHREADS) {
                size_t o = (size_t)(b * N_ + c * CHUNK + j) * 3;
                float xx = mu0[o], yy = mu0[o+1], zz = mu0[o+2];
                chk[j] = make_float4(xx, yy, zz, (xx*xx + yy*yy) + zz*zz);
            }
        }
        __syncthreads();

        int colbase = c * CHUNK;
        if (c == selfc)
            do_chunk4<true >(chk, seg, colbase, n0, n1, n2, n3,
                             a00,a01,a02, a10,a11,a12, a20,a21,a22, a30,a31,a32,
                             k0, k1, k2, k3);
        else
            do_chunk4<false>(chk, seg, colbase, n0, n1, n2, n3,
                             a00,a01,a02, a10,a11,a12, a20,a21,a22, a30,a31,a32,
                             k0, k1, k2, k3);
    }

    // in-wave butterfly merge over the 3 seg bits
    wave_merge8(k0);
    wave_merge8(k1);
    wave_merge8(k2);
    wave_merge8(k3);

    int lane = tid & 63;
    int w    = tid >> 6;                          // wave 0..7
    if (lane < SLOTS) {
        #pragma unroll
        for (int i = 0; i < 8; ++i) {
            shk[lane            ][w * 8 + i] = k0[i];
            shk[lane +     SLOTS][w * 8 + i] = k1[i];
            shk[lane + 2 * SLOTS][w * 8 + i] = k2[i];
            shk[lane + 3 * SLOTS][w * 8 + i] = k3[i];
        }
    }
    __syncthreads();

    if (tid < ROWSB) {                             // one lane per row: 8 sorted lists -> 8
        int r = tid;
        int nn = rb * ROWSB + r;
        float best[8];
        #pragma unroll
        for (int i = 0; i < 8; ++i) best[i] = 3.0e38f;
        #pragma unroll
        for (int w2 = 0; w2 < 8; ++w2) {
            float s[8];
            #pragma unroll
            for (int i = 0; i < 8; ++i) s[i] = shk[r][w2 * 8 + i];
            bmerge8(best, s);
        }

        // restore d2 = sqn + s for the selected 8
        float cn;
        if (useF4) {
            cn = mu4[b * N_ + nn].w;
        } else {
            size_t so = (size_t)(b * N_ + nn) * 3;
            float xx = mu0[so], yy = mu0[so+1], zz = mu0[so+2];
            cn = (xx*xx + yy*yy) + zz*zz;
        }

        double s0 = sqrt(fmax((double)(cn + best[0]), 0.0)), s1 = sqrt(fmax((double)(cn + best[1]), 0.0));
        double s2 = sqrt(fmax((double)(cn + best[2]), 0.0)), s3 = sqrt(fmax((double)(cn + best[3]), 0.0));
        double s4 = sqrt(fmax((double)(cn + best[4]), 0.0)), s5 = sqrt(fmax((double)(cn + best[5]), 0.0));
        double s6 = sqrt(fmax((double)(cn + best[6]), 0.0)), s7 = sqrt(fmax((double)(cn + best[7]), 0.0));
        double d_mean = (((s0 + s1) + (s2 + s3)) + ((s4 + s5) + (s6 + s7))) / 8.0;

        double sigma = fmin(fmax(1.5 * d_mean, 1e-3), 100.0);
        double spacing = sigma * sigma + 1e-6;

        int p = (int)out[(size_t)B_ * N_ * 12 + (size_t)(b * N_ + nn)];
        const float* S = Sig_p + (size_t)(b * K_ + p) * 9;
        double s00 = (double)S[0];
        double s01 = 0.5 * ((double)S[1] + (double)S[3]);
        double s02 = 0.5 * ((double)S[2] + (double)S[6]);
        double s11 = (double)S[4];
        double s12 = 0.5 * ((double)S[5] + (double)S[7]);
        double s22 = (double)S[8];

        const double BETA = 0.85;
        const double OMB  = 1.0 - 0.85;
        double nm = (double)node_mask[b * N_ + nn];

        double d00 = (BETA * (s00 + 1e-6) + OMB * spacing) + 1e-6;
        double d11 = (BETA * (s11 + 1e-6) + OMB * spacing) + 1e-6;
        double d22 = (BETA * (s22 + 1e-6) + OMB * spacing) + 1e-6;
        double o01 = BETA * s01;
        double o02 = BETA * s02;
        double o12 = BETA * s12;

        float* Sg = out + (size_t)B_ * N_ * 3 + (size_t)(b * N_ + nn) * 9;
        Sg[0] = (float)(d00 * nm); Sg[1] = (float)(o01 * nm); Sg[2] = (float)(o02 * nm);
        Sg[3] = (float)(o01 * nm); Sg[4] = (float)(d11 * nm); Sg[5] = (float)(o12 * nm);
        Sg[6] = (float)(o02 * nm); Sg[7] = (float)(o12 * nm); Sg[8] = (float)(d22 * nm);
    }
}

// ---------------- launch ----------------
extern "C" void kernel_launch(void* const* d_in, const int* in_sizes, int n_in,
                              void* d_out, int out_size, void* d_ws, size_t ws_size,
                              hipStream_t stream)
{
    const float* mu_p        = (const float*)d_in[0];
    const float* Sig_p       = (const float*)d_in[1];
    const float* occ         = (const float*)d_in[2];
    const float* mask_parent = (const float*)d_in[3];
    const float* node_mask   = (const float*)d_in[4];
    const float* z           = (const float*)d_in[5];
    float* out = (float*)d_out;

    // float4 mu0 copy (with squared norm in .w) lives in d_ws.
    int useF4 = (ws_size >= (size_t)B_ * N_ * sizeof(float4)) ? 1 : 0;
    float4* mu4 = (float4*)d_ws;

    fused_kernel<<<B_ * 8, 512, 0, stream>>>(mu_p, Sig_p, occ, mask_parent,
                                             node_mask, z, out, mu4, useF4);
    knn_kernel<<<B_ * (N_ / ROWSB), KTHREADS, 0, stream>>>(Sig_p, node_mask,
                                                           mu4, useF4, out);
}

// Round 4
// 49.745 us; speedup vs baseline: 1.1478x; 1.0014x over previous
//
#include <hip/hip_runtime.h>
#include <math.h>

#define B_ 4
#define K_ 512
#define N_ 4096
#define M_ 4

#define KTHREADS 512
#define SLOTS 8                 // slot = tid & 7 ; rows n0=slot, n1=slot+8
#define SEGS 64                 // seg  = tid >> 3
#define ROWS 16                 // rows per block (SLOTS * 2)
#define CHUNK 1024
#define NCHUNK (N_ / CHUNK)     // 4
#define CPL (CHUNK / SEGS)      // 16 columns per lane per chunk
#define BIGF 3.0e38f

// ---------------- scalar-only sorting networks (NO arrays -> no allocas -> no scratch) ----
// CSW: x=min, y=max
#define CSW(x,y) { float _lo = fminf(x,y); y = fmaxf(x,y); x = _lo; }

// Batcher odd-even mergesort, 8 elements, 19 comparators (same network as prior rounds).
#define SORT8S(s0,s1,s2,s3,s4,s5,s6,s7) \
    CSW(s0,s1) CSW(s2,s3) CSW(s4,s5) CSW(s6,s7) \
    CSW(s0,s2) CSW(s1,s3) CSW(s4,s6) CSW(s5,s7) \
    CSW(s1,s2) CSW(s5,s6) \
    CSW(s0,s4) CSW(s1,s5) CSW(s2,s6) CSW(s3,s7) \
    CSW(s2,s4) CSW(s3,s5) \
    CSW(s1,s2) CSW(s3,s4) CSW(s5,s6)

// K (sorted asc) := lowest-8 of union(K, S) where S sorted asc; result sorted asc.
// Identical dataflow to prior bmerge8.
#define BMERGE8S(K0,K1,K2,K3,K4,K5,K6,K7, S0,S1,S2,S3,S4,S5,S6,S7) \
    K0 = fminf(K0,S7); K1 = fminf(K1,S6); K2 = fminf(K2,S5); K3 = fminf(K3,S4); \
    K4 = fminf(K4,S3); K5 = fminf(K5,S2); K6 = fminf(K6,S1); K7 = fminf(K7,S0); \
    CSW(K0,K4) CSW(K1,K5) CSW(K2,K6) CSW(K3,K7) \
    CSW(K0,K2) CSW(K1,K3) CSW(K4,K6) CSW(K5,K7) \
    CSW(K0,K1) CSW(K2,K3) CSW(K4,K5) CSW(K6,K7)

// butterfly wave-merge step: merge with lane^off partner's sorted list
#define WMERGE(K0,K1,K2,K3,K4,K5,K6,K7, off) { \
    float _b0 = __shfl_xor(K0, off, 64); float _b1 = __shfl_xor(K1, off, 64); \
    float _b2 = __shfl_xor(K2, off, 64); float _b3 = __shfl_xor(K3, off, 64); \
    float _b4 = __shfl_xor(K4, off, 64); float _b5 = __shfl_xor(K5, off, 64); \
    float _b6 = __shfl_xor(K6, off, 64); float _b7 = __shfl_xor(K7, off, 64); \
    BMERGE8S(K0,K1,K2,K3,K4,K5,K6,K7, _b0,_b1,_b2,_b3,_b4,_b5,_b6,_b7) }

// ---------------- Kernel 1: FUSED quota + Cholesky + sample ----------------
// (unchanged — passing, absmax 0.0078)
__global__ __launch_bounds__(512) void fused_kernel(const float* __restrict__ mu_p,
                                                    const float* __restrict__ Sig_p,
                                                    const float* __restrict__ occ,
                                                    const float* __restrict__ mask_parent,
                                                    const float* __restrict__ node_mask,
                                                    const float* __restrict__ z,
                                                    float* __restrict__ out,
                                                    float4* __restrict__ mu4,
                                                    int useF4)
{
    __shared__ double sh_a[K_];                    // pi, then base
    __shared__ double sh_part[32];
    __shared__ alignas(16) double sh_frac[K_];     // exact f64 fracs (fallback path)
    __shared__ alignas(16) float  sh_ffr[K_];      // f32 shadow for the fast rank
    __shared__ float  csf[K_];                     // float cumsum for the search
    __shared__ double Lsh[K_][6];                  // 24 KB Cholesky table
    __shared__ int    sh_wsum[8];
    __shared__ double s_S;
    __shared__ int    s_rem;

    int b  = blockIdx.x >> 3;          // /8
    int rb = blockIdx.x & 7;
    int k  = threadIdx.x;              // 0..511 == parent index

    // ---- quota (np-f64 exact, parallel) ----
    float mk = mask_parent[b * K_ + k];
    bool valid = mk > 0.5f;
    double pi = valid ? (double)occ[b * K_ + k] : 0.0;
    sh_a[k] = pi;
    __syncthreads();

    if (k < 32) {                       // numpy's exact pairwise association
        const double* a = sh_a + (k >> 3) * 128;
        int j = k & 7;
        double r = a[j];
        for (int i = 8; i < 128; i += 8) r += a[j + i];
        sh_part[k] = r;
    }
    __syncthreads();
    if (k == 0) {
        double pw[4];
        #pragma unroll
        for (int blk = 0; blk < 4; ++blk) {
            const double* p = sh_part + blk * 8;
            pw[blk] = ((p[0]+p[1])+(p[2]+p[3]))+((p[4]+p[5])+(p[6]+p[7]));
        }
        s_S = fmax((pw[0]+pw[1])+(pw[2]+pw[3]), 1e-9);
    }
    __syncthreads();

    double raw  = (pi / s_S) * 4096.0;
    double base = floor(raw);
    double frac = valid ? (raw - base) : -1e9;
    sh_frac[k] = frac;
    sh_ffr[k]  = (float)frac;
    __syncthreads();
    sh_a[k] = base;
    __syncthreads();
    if (k < 32) {
        const double* a = sh_a + (k >> 3) * 128;
        int j = k & 7;
        double r = a[j];
        for (int i = 8; i < 128; i += 8) r += a[j + i];
        sh_part[k] = r;
    }
    __syncthreads();
    if (k == 0) {
        double pw[4];
        #pragma unroll
        for (int blk = 0; blk < 4; ++blk) {
            const double* p = sh_part + blk * 8;
            pw[blk] = ((p[0]+p[1])+(p[2]+p[3]))+((p[4]+p[5])+(p[6]+p[7]));
        }
        s_rem = (int)(4096.0 - ((pw[0]+pw[1])+(pw[2]+pw[3])));
    }
    __syncthreads();

    // ---- stable rank in descending frac ----
    int nkv = 0;
    if (valid) {
        float fl = (float)frac;
        int rank = 0, eq = 0;
        const float4* f4 = reinterpret_cast<const float4*>(sh_ffr);
        #pragma unroll 4
        for (int j4 = 0; j4 < K_ / 4; ++j4) {
            float4 q = f4[j4];
            rank += (q.x > fl) ? 1 : 0;  eq += (q.x == fl) ? 1 : 0;
            rank += (q.y > fl) ? 1 : 0;  eq += (q.y == fl) ? 1 : 0;
            rank += (q.z > fl) ? 1 : 0;  eq += (q.z == fl) ? 1 : 0;
            rank += (q.w > fl) ? 1 : 0;  eq += (q.w == fl) ? 1 : 0;
        }
        if (__builtin_expect(eq != 1, 0)) {      // float collision: exact f64 rank
            double f = frac;
            rank = 0;
            for (int j = 0; j < K_; ++j) {
                double fj = sh_frac[j];
                rank += ((fj > f) || (fj == f && j < k)) ? 1 : 0;
            }
        }
        nkv = (int)base + (rank < s_rem ? 1 : 0);
    }

    // ---- inclusive scan: wave shfl scan + cross-wave offsets (integer-exact) ----
    {
        int lane = k & 63;
        int w    = k >> 6;
        int v = nkv;
        #pragma unroll
        for (int off = 1; off < 64; off <<= 1) {
            int t = __shfl_up(v, off, 64);
            v += (lane >= off) ? t : 0;
        }
        if (lane == 63) sh_wsum[w] = v;
        __syncthreads();
        int woff = 0;
        #pragma unroll
        for (int i = 0; i < 7; ++i) woff += (i < w) ? sh_wsum[i] : 0;
        csf[k] = (float)(v + woff);
    }

    // ---- per-parent Cholesky into LDS (identical f64 formula) ----
    {
        const float* S = Sig_p + (size_t)(b * K_ + k) * 9;
        double s00 = (double)S[0] + 1e-6;
        double s01 = 0.5 * ((double)S[1] + (double)S[3]);
        double s02 = 0.5 * ((double)S[2] + (double)S[6]);
        double s11 = (double)S[4] + 1e-6;
        double s12 = 0.5 * ((double)S[5] + (double)S[7]);
        double s22 = (double)S[8] + 1e-6;

        const double eps = 1e-6;
        double l00 = sqrt(fmax(s00, eps));
        double l10 = s01 / fmax(l00, eps);
        double l20 = s02 / fmax(l00, eps);
        double l11 = sqrt(fmax(s11 - l10 * l10, eps));
        double l21 = (s12 - l20 * l10) / fmax(l11, eps);
        double l22 = sqrt(fmax(s22 - l20 * l20 - l21 * l21, eps));

        Lsh[k][0] = l00; Lsh[k][1] = l10; Lsh[k][2] = l20;
        Lsh[k][3] = l11; Lsh[k][4] = l21; Lsh[k][5] = l22;
    }
    __syncthreads();   // covers csf + Lsh writes

    // ---- sample node n (LDS binary search + LDS L) ----
    int n = rb * 512 + k;
    float nf = (float)n;
    int lo = 0, hi = K_;
    while (lo < hi) {
        int mid = (lo + hi) >> 1;
        if (csf[mid] <= nf) lo = mid + 1; else hi = mid;
    }
    int p = lo < (K_ - 1) ? lo : (K_ - 1);

    double l00 = Lsh[p][0], l10 = Lsh[p][1], l20 = Lsh[p][2];
    double l11 = Lsh[p][3], l21 = Lsh[p][4], l22 = Lsh[p][5];

    const float* zp = z + (size_t)(b * N_ + n) * (M_ * 3);
    double bestScore = 1e30;
    int pick = 0;
    #pragma unroll
    for (int m = 0; m < M_; ++m) {
        double z0 = (double)zp[m*3+0], z1 = (double)zp[m*3+1], z2 = (double)zp[m*3+2];
        double maha2 = (z0 * z0 + z1 * z1) + z2 * z2;
        double score = (maha2 <= 7.815) ? (double)m : (1e6 + maha2);
        if (score < bestScore) { bestScore = score; pick = m; }
    }

    double z0 = (double)zp[pick*3+0], z1 = (double)zp[pick*3+1], z2 = (double)zp[pick*3+2];
    const float* mu = mu_p + (size_t)(b * K_ + p) * 3;
    double nm = (double)node_mask[b * N_ + n];
    double c0 = ((double)mu[0] + ((l00 * z0)))                       * nm;
    double c1 = ((double)mu[1] + ((l10 * z0 + l11 * z1)))            * nm;
    double c2 = ((double)mu[2] + ((l20 * z0 + l21 * z1) + l22 * z2)) * nm;

    size_t o = (size_t)(b * N_ + n) * 3;
    float f0 = (float)c0, f1 = (float)c1, f2 = (float)c2;
    out[o + 0] = f0;
    out[o + 1] = f1;
    out[o + 2] = f2;
    if (useF4) {
        float sq = (f0 * f0 + f1 * f1) + f2 * f2;
        mu4[b * N_ + n] = make_float4(f0, f1, f2, sq);
    }
    out[(size_t)B_ * N_ * 12 + (size_t)(b * N_ + n)] = (float)p;   // parent_idx output
}

// one column u of the current 8-batch: dist to rows n0,n1 (+ optional self-mask)
#define LOADU(u, SQ) { \
    int j_ = (gb8 + u) * SEGS + seg; \
    float4 q_ = chk[j_]; \
    s##u = fmaf(a00, q_.x, fmaf(a01, q_.y, fmaf(a02, q_.z, q_.w))); \
    r##u = fmaf(a10, q_.x, fmaf(a11, q_.y, fmaf(a12, q_.z, q_.w))); \
    if (SQ) { int c_ = colbase + j_; \
        s##u = (c_ == n0) ? BIGF : s##u; \
        r##u = (c_ == n1) ? BIGF : r##u; } }

#define GROUP8(SQ) { \
    float s0,s1,s2,s3,s4,s5,s6,s7, r0,r1,r2,r3,r4,r5,r6,r7; \
    LOADU(0,SQ) LOADU(1,SQ) LOADU(2,SQ) LOADU(3,SQ) \
    LOADU(4,SQ) LOADU(5,SQ) LOADU(6,SQ) LOADU(7,SQ) \
    SORT8S(s0,s1,s2,s3,s4,s5,s6,s7) \
    BMERGE8S(ka0,ka1,ka2,ka3,ka4,ka5,ka6,ka7, s0,s1,s2,s3,s4,s5,s6,s7) \
    SORT8S(r0,r1,r2,r3,r4,r5,r6,r7) \
    BMERGE8S(kb0,kb1,kb2,kb3,kb4,kb5,kb6,kb7, r0,r1,r2,r3,r4,r5,r6,r7) }

// ---------------- Kernel 2: kNN — 512 thr, 16 rows/block, 1024 blocks ----------------
// All selection state in named scalars (macros, no allocas): scratch structurally
// impossible. Grid 1024 blocks -> 4 blocks/CU; target VGPR <=~80 for 7-8 waves/SIMD.
__global__ __launch_bounds__(KTHREADS, 4) void knn_kernel(const float* __restrict__ Sig_p,
                                                          const float* __restrict__ node_mask,
                                                          const float4* __restrict__ mu4,
                                                          int useF4,
                                                          float* __restrict__ out)
{
    __shared__ float4 chk[CHUNK];                 // 16 KB staged columns (+sq in w)
    __shared__ float  shk[ROWS][8 * 8 + 1];       // 16 x 65 = 4.2 KB wave partials

    int b   = blockIdx.x / (N_ / ROWS);           // 256 blocks per batch
    int rb  = blockIdx.x % (N_ / ROWS);
    int tid = threadIdx.x;
    int slot = tid & (SLOTS - 1);                 // 0..7
    int seg  = tid >> 3;                          // 0..63

    const float* mu0 = out;                       // [B,N,3]
    int n0 = rb * ROWS + slot;
    int n1 = n0 + SLOTS;

    float x0, y0, z0v, x1, y1, z1v;
    if (useF4) {
        float4 p0 = mu4[b * N_ + n0]; x0 = p0.x; y0 = p0.y; z0v = p0.z;
        float4 p1 = mu4[b * N_ + n1]; x1 = p1.x; y1 = p1.y; z1v = p1.z;
    } else {
        size_t so0 = (size_t)(b * N_ + n0) * 3;
        size_t so1 = (size_t)(b * N_ + n1) * 3;
        x0 = mu0[so0]; y0 = mu0[so0+1]; z0v = mu0[so0+2];
        x1 = mu0[so1]; y1 = mu0[so1+1]; z1v = mu0[so1+2];
    }
    float a00 = -2.0f*x0, a01 = -2.0f*y0, a02 = -2.0f*z0v;
    float a10 = -2.0f*x1, a11 = -2.0f*y1, a12 = -2.0f*z1v;

    float ka0=BIGF,ka1=BIGF,ka2=BIGF,ka3=BIGF,ka4=BIGF,ka5=BIGF,ka6=BIGF,ka7=BIGF;
    float kb0=BIGF,kb1=BIGF,kb2=BIGF,kb3=BIGF,kb4=BIGF,kb5=BIGF,kb6=BIGF,kb7=BIGF;

    int selfc = (rb * ROWS) >> 10;                // chunk containing rows n0,n1

    for (int c = 0; c < NCHUNK; ++c) {
        __syncthreads();
        if (useF4) {
            for (int j = tid; j < CHUNK; j += KTHREADS)
                chk[j] = mu4[b * N_ + c * CHUNK + j];
        } else {
            for (int j = tid; j < CHUNK; j += KTHREADS) {
                size_t o = (size_t)(b * N_ + c * CHUNK + j) * 3;
                float xx = mu0[o], yy = mu0[o+1], zz = mu0[o+2];
                chk[j] = make_float4(xx, yy, zz, (xx*xx + yy*yy) + zz*zz);
            }
        }
        __syncthreads();

        int colbase = c * CHUNK;
        if (c == selfc) {
            { int gb8 = 0; GROUP8(1) }
            { int gb8 = 8; GROUP8(1) }
        } else {
            { int gb8 = 0; GROUP8(0) }
            { int gb8 = 8; GROUP8(0) }
        }
    }

    // in-wave butterfly merge over the 3 seg bits
    WMERGE(ka0,ka1,ka2,ka3,ka4,ka5,ka6,ka7, 8)
    WMERGE(ka0,ka1,ka2,ka3,ka4,ka5,ka6,ka7, 16)
    WMERGE(ka0,ka1,ka2,ka3,ka4,ka5,ka6,ka7, 32)
    WMERGE(kb0,kb1,kb2,kb3,kb4,kb5,kb6,kb7, 8)
    WMERGE(kb0,kb1,kb2,kb3,kb4,kb5,kb6,kb7, 16)
    WMERGE(kb0,kb1,kb2,kb3,kb4,kb5,kb6,kb7, 32)

    int lane = tid & 63;
    int w    = tid >> 6;                          // wave 0..7
    if (lane < SLOTS) {
        shk[lane][w*8+0] = ka0; shk[lane][w*8+1] = ka1;
        shk[lane][w*8+2] = ka2; shk[lane][w*8+3] = ka3;
        shk[lane][w*8+4] = ka4; shk[lane][w*8+5] = ka5;
        shk[lane][w*8+6] = ka6; shk[lane][w*8+7] = ka7;
        shk[lane+SLOTS][w*8+0] = kb0; shk[lane+SLOTS][w*8+1] = kb1;
        shk[lane+SLOTS][w*8+2] = kb2; shk[lane+SLOTS][w*8+3] = kb3;
        shk[lane+SLOTS][w*8+4] = kb4; shk[lane+SLOTS][w*8+5] = kb5;
        shk[lane+SLOTS][w*8+6] = kb6; shk[lane+SLOTS][w*8+7] = kb7;
    }
    __syncthreads();

    if (tid < ROWS) {                              // one lane per row: 8 sorted lists -> 8
        int r = tid;
        int nn = rb * ROWS + r;
        float e0=BIGF,e1=BIGF,e2=BIGF,e3=BIGF,e4=BIGF,e5=BIGF,e6=BIGF,e7=BIGF;
        #pragma unroll
        for (int w2 = 0; w2 < 8; ++w2) {
            float b0 = shk[r][w2*8+0], b1 = shk[r][w2*8+1];
            float b2 = shk[r][w2*8+2], b3 = shk[r][w2*8+3];
            float b4 = shk[r][w2*8+4], b5 = shk[r][w2*8+5];
            float b6 = shk[r][w2*8+6], b7 = shk[r][w2*8+7];
            BMERGE8S(e0,e1,e2,e3,e4,e5,e6,e7, b0,b1,b2,b3,b4,b5,b6,b7)
        }

        // restore d2 = sqn + s for the selected 8
        float cn;
        if (useF4) {
            cn = mu4[b * N_ + nn].w;
        } else {
            size_t so = (size_t)(b * N_ + nn) * 3;
            float xx = mu0[so], yy = mu0[so+1], zz = mu0[so+2];
            cn = (xx*xx + yy*yy) + zz*zz;
        }

        double s0 = sqrt(fmax((double)(cn + e0), 0.0)), s1 = sqrt(fmax((double)(cn + e1), 0.0));
        double s2 = sqrt(fmax((double)(cn + e2), 0.0)), s3 = sqrt(fmax((double)(cn + e3), 0.0));
        double s4 = sqrt(fmax((double)(cn + e4), 0.0)), s5 = sqrt(fmax((double)(cn + e5), 0.0));
        double s6 = sqrt(fmax((double)(cn + e6), 0.0)), s7 = sqrt(fmax((double)(cn + e7), 0.0));
        double d_mean = (((s0 + s1) + (s2 + s3)) + ((s4 + s5) + (s6 + s7))) / 8.0;

        double sigma = fmin(fmax(1.5 * d_mean, 1e-3), 100.0);
        double spacing = sigma * sigma + 1e-6;

        int p = (int)out[(size_t)B_ * N_ * 12 + (size_t)(b * N_ + nn)];
        const float* S = Sig_p + (size_t)(b * K_ + p) * 9;
        double s00 = (double)S[0];
        double s01 = 0.5 * ((double)S[1] + (double)S[3]);
        double s02 = 0.5 * ((double)S[2] + (double)S[6]);
        double s11 = (double)S[4];
        double s12 = 0.5 * ((double)S[5] + (double)S[7]);
        double s22 = (double)S[8];

        const double BETA = 0.85;
        const double OMB  = 1.0 - 0.85;
        double nm = (double)node_mask[b * N_ + nn];

        double d00 = (BETA * (s00 + 1e-6) + OMB * spacing) + 1e-6;
        double d11 = (BETA * (s11 + 1e-6) + OMB * spacing) + 1e-6;
        double d22 = (BETA * (s22 + 1e-6) + OMB * spacing) + 1e-6;
        double o01 = BETA * s01;
        double o02 = BETA * s02;
        double o12 = BETA * s12;

        float* Sg = out + (size_t)B_ * N_ * 3 + (size_t)(b * N_ + nn) * 9;
        Sg[0] = (float)(d00 * nm); Sg[1] = (float)(o01 * nm); Sg[2] = (float)(o02 * nm);
        Sg[3] = (float)(o01 * nm); Sg[4] = (float)(d11 * nm); Sg[5] = (float)(o12 * nm);
        Sg[6] = (float)(o02 * nm); Sg[7] = (float)(o12 * nm); Sg[8] = (float)(d22 * nm);
    }
}

// ---------------- launch ----------------
extern "C" void kernel_launch(void* const* d_in, const int* in_sizes, int n_in,
                              void* d_out, int out_size, void* d_ws, size_t ws_size,
                              hipStream_t stream)
{
    const float* mu_p        = (const float*)d_in[0];
    const float* Sig_p       = (const float*)d_in[1];
    const float* occ         = (const float*)d_in[2];
    const float* mask_parent = (const float*)d_in[3];
    const float* node_mask   = (const float*)d_in[4];
    const float* z           = (const float*)d_in[5];
    float* out = (float*)d_out;

    // float4 mu0 copy (with squared norm in .w) lives in d_ws.
    int useF4 = (ws_size >= (size_t)B_ * N_ * sizeof(float4)) ? 1 : 0;
    float4* mu4 = (float4*)d_ws;

    fused_kernel<<<B_ * 8, 512, 0, stream>>>(mu_p, Sig_p, occ, mask_parent,
                                             node_mask, z, out, mu4, useF4);
    knn_kernel<<<B_ * (N_ / ROWS), KTHREADS, 0, stream>>>(Sig_p, node_mask,
                                                          mu4, useF4, out);
}

// Round 5
// 47.147 us; speedup vs baseline: 1.2110x; 1.0551x over previous
//
#include <hip/hip_runtime.h>
#include <math.h>

#define B_ 4
#define K_ 512
#define N_ 4096
#define M_ 4

#define KTHREADS 512
#define SLOTS 8                 // slot = tid & 7 ; rows n0=slot, n1=slot+8
#define SEGS 64                 // seg  = tid >> 3
#define ROWS 16                 // rows per block (SLOTS * 2)
#define CHUNK 1024
#define NCHUNK (N_ / CHUNK)     // 4
#define BIGF 3.0e38f

// ---------------- scalar-only sorting networks (NO arrays -> no allocas -> no scratch) ----
// CSW: x=min, y=max
#define CSW(x,y) { float _lo = fminf(x,y); y = fmaxf(x,y); x = _lo; }

// Batcher odd-even mergesort, 8 elements, 19 comparators.
#define SORT8S(s0,s1,s2,s3,s4,s5,s6,s7) \
    CSW(s0,s1) CSW(s2,s3) CSW(s4,s5) CSW(s6,s7) \
    CSW(s0,s2) CSW(s1,s3) CSW(s4,s6) CSW(s5,s7) \
    CSW(s1,s2) CSW(s5,s6) \
    CSW(s0,s4) CSW(s1,s5) CSW(s2,s6) CSW(s3,s7) \
    CSW(s2,s4) CSW(s3,s5) \
    CSW(s1,s2) CSW(s3,s4) CSW(s5,s6)

// K (sorted asc) := lowest-8 of union(K, S) where S sorted asc; result sorted asc.
#define BMERGE8S(K0,K1,K2,K3,K4,K5,K6,K7, S0,S1,S2,S3,S4,S5,S6,S7) \
    K0 = fminf(K0,S7); K1 = fminf(K1,S6); K2 = fminf(K2,S5); K3 = fminf(K3,S4); \
    K4 = fminf(K4,S3); K5 = fminf(K5,S2); K6 = fminf(K6,S1); K7 = fminf(K7,S0); \
    CSW(K0,K4) CSW(K1,K5) CSW(K2,K6) CSW(K3,K7) \
    CSW(K0,K2) CSW(K1,K3) CSW(K4,K6) CSW(K5,K7) \
    CSW(K0,K1) CSW(K2,K3) CSW(K4,K5) CSW(K6,K7)

// butterfly wave-merge step: merge with lane^off partner's sorted list
#define WMERGE(K0,K1,K2,K3,K4,K5,K6,K7, off) { \
    float _b0 = __shfl_xor(K0, off, 64); float _b1 = __shfl_xor(K1, off, 64); \
    float _b2 = __shfl_xor(K2, off, 64); float _b3 = __shfl_xor(K3, off, 64); \
    float _b4 = __shfl_xor(K4, off, 64); float _b5 = __shfl_xor(K5, off, 64); \
    float _b6 = __shfl_xor(K6, off, 64); float _b7 = __shfl_xor(K7, off, 64); \
    BMERGE8S(K0,K1,K2,K3,K4,K5,K6,K7, _b0,_b1,_b2,_b3,_b4,_b5,_b6,_b7) }

// ---------------- Kernel 1: FUSED quota + Cholesky + sample ----------------
// (unchanged — passing, absmax 0.0078)
__global__ __launch_bounds__(512) void fused_kernel(const float* __restrict__ mu_p,
                                                    const float* __restrict__ Sig_p,
                                                    const float* __restrict__ occ,
                                                    const float* __restrict__ mask_parent,
                                                    const float* __restrict__ node_mask,
                                                    const float* __restrict__ z,
                                                    float* __restrict__ out,
                                                    float4* __restrict__ mu4,
                                                    int useF4)
{
    __shared__ double sh_a[K_];                    // pi, then base
    __shared__ double sh_part[32];
    __shared__ alignas(16) double sh_frac[K_];     // exact f64 fracs (fallback path)
    __shared__ alignas(16) float  sh_ffr[K_];      // f32 shadow for the fast rank
    __shared__ float  csf[K_];                     // float cumsum for the search
    __shared__ double Lsh[K_][6];                  // 24 KB Cholesky table
    __shared__ int    sh_wsum[8];
    __shared__ double s_S;
    __shared__ int    s_rem;

    int b  = blockIdx.x >> 3;          // /8
    int rb = blockIdx.x & 7;
    int k  = threadIdx.x;              // 0..511 == parent index

    // ---- quota (np-f64 exact, parallel) ----
    float mk = mask_parent[b * K_ + k];
    bool valid = mk > 0.5f;
    double pi = valid ? (double)occ[b * K_ + k] : 0.0;
    sh_a[k] = pi;
    __syncthreads();

    if (k < 32) {                       // numpy's exact pairwise association
        const double* a = sh_a + (k >> 3) * 128;
        int j = k & 7;
        double r = a[j];
        for (int i = 8; i < 128; i += 8) r += a[j + i];
        sh_part[k] = r;
    }
    __syncthreads();
    if (k == 0) {
        double pw[4];
        #pragma unroll
        for (int blk = 0; blk < 4; ++blk) {
            const double* p = sh_part + blk * 8;
            pw[blk] = ((p[0]+p[1])+(p[2]+p[3]))+((p[4]+p[5])+(p[6]+p[7]));
        }
        s_S = fmax((pw[0]+pw[1])+(pw[2]+pw[3]), 1e-9);
    }
    __syncthreads();

    double raw  = (pi / s_S) * 4096.0;
    double base = floor(raw);
    double frac = valid ? (raw - base) : -1e9;
    sh_frac[k] = frac;
    sh_ffr[k]  = (float)frac;
    __syncthreads();
    sh_a[k] = base;
    __syncthreads();
    if (k < 32) {
        const double* a = sh_a + (k >> 3) * 128;
        int j = k & 7;
        double r = a[j];
        for (int i = 8; i < 128; i += 8) r += a[j + i];
        sh_part[k] = r;
    }
    __syncthreads();
    if (k == 0) {
        double pw[4];
        #pragma unroll
        for (int blk = 0; blk < 4; ++blk) {
            const double* p = sh_part + blk * 8;
            pw[blk] = ((p[0]+p[1])+(p[2]+p[3]))+((p[4]+p[5])+(p[6]+p[7]));
        }
        s_rem = (int)(4096.0 - ((pw[0]+pw[1])+(pw[2]+pw[3])));
    }
    __syncthreads();

    // ---- stable rank in descending frac ----
    int nkv = 0;
    if (valid) {
        float fl = (float)frac;
        int rank = 0, eq = 0;
        const float4* f4 = reinterpret_cast<const float4*>(sh_ffr);
        #pragma unroll 4
        for (int j4 = 0; j4 < K_ / 4; ++j4) {
            float4 q = f4[j4];
            rank += (q.x > fl) ? 1 : 0;  eq += (q.x == fl) ? 1 : 0;
            rank += (q.y > fl) ? 1 : 0;  eq += (q.y == fl) ? 1 : 0;
            rank += (q.z > fl) ? 1 : 0;  eq += (q.z == fl) ? 1 : 0;
            rank += (q.w > fl) ? 1 : 0;  eq += (q.w == fl) ? 1 : 0;
        }
        if (__builtin_expect(eq != 1, 0)) {      // float collision: exact f64 rank
            double f = frac;
            rank = 0;
            for (int j = 0; j < K_; ++j) {
                double fj = sh_frac[j];
                rank += ((fj > f) || (fj == f && j < k)) ? 1 : 0;
            }
        }
        nkv = (int)base + (rank < s_rem ? 1 : 0);
    }

    // ---- inclusive scan: wave shfl scan + cross-wave offsets (integer-exact) ----
    {
        int lane = k & 63;
        int w    = k >> 6;
        int v = nkv;
        #pragma unroll
        for (int off = 1; off < 64; off <<= 1) {
            int t = __shfl_up(v, off, 64);
            v += (lane >= off) ? t : 0;
        }
        if (lane == 63) sh_wsum[w] = v;
        __syncthreads();
        int woff = 0;
        #pragma unroll
        for (int i = 0; i < 7; ++i) woff += (i < w) ? sh_wsum[i] : 0;
        csf[k] = (float)(v + woff);
    }

    // ---- per-parent Cholesky into LDS (identical f64 formula) ----
    {
        const float* S = Sig_p + (size_t)(b * K_ + k) * 9;
        double s00 = (double)S[0] + 1e-6;
        double s01 = 0.5 * ((double)S[1] + (double)S[3]);
        double s02 = 0.5 * ((double)S[2] + (double)S[6]);
        double s11 = (double)S[4] + 1e-6;
        double s12 = 0.5 * ((double)S[5] + (double)S[7]);
        double s22 = (double)S[8] + 1e-6;

        const double eps = 1e-6;
        double l00 = sqrt(fmax(s00, eps));
        double l10 = s01 / fmax(l00, eps);
        double l20 = s02 / fmax(l00, eps);
        double l11 = sqrt(fmax(s11 - l10 * l10, eps));
        double l21 = (s12 - l20 * l10) / fmax(l11, eps);
        double l22 = sqrt(fmax(s22 - l20 * l20 - l21 * l21, eps));

        Lsh[k][0] = l00; Lsh[k][1] = l10; Lsh[k][2] = l20;
        Lsh[k][3] = l11; Lsh[k][4] = l21; Lsh[k][5] = l22;
    }
    __syncthreads();   // covers csf + Lsh writes

    // ---- sample node n (LDS binary search + LDS L) ----
    int n = rb * 512 + k;
    float nf = (float)n;
    int lo = 0, hi = K_;
    while (lo < hi) {
        int mid = (lo + hi) >> 1;
        if (csf[mid] <= nf) lo = mid + 1; else hi = mid;
    }
    int p = lo < (K_ - 1) ? lo : (K_ - 1);

    double l00 = Lsh[p][0], l10 = Lsh[p][1], l20 = Lsh[p][2];
    double l11 = Lsh[p][3], l21 = Lsh[p][4], l22 = Lsh[p][5];

    const float* zp = z + (size_t)(b * N_ + n) * (M_ * 3);
    double bestScore = 1e30;
    int pick = 0;
    #pragma unroll
    for (int m = 0; m < M_; ++m) {
        double z0 = (double)zp[m*3+0], z1 = (double)zp[m*3+1], z2 = (double)zp[m*3+2];
        double maha2 = (z0 * z0 + z1 * z1) + z2 * z2;
        double score = (maha2 <= 7.815) ? (double)m : (1e6 + maha2);
        if (score < bestScore) { bestScore = score; pick = m; }
    }

    double z0 = (double)zp[pick*3+0], z1 = (double)zp[pick*3+1], z2 = (double)zp[pick*3+2];
    const float* mu = mu_p + (size_t)(b * K_ + p) * 3;
    double nm = (double)node_mask[b * N_ + n];
    double c0 = ((double)mu[0] + ((l00 * z0)))                       * nm;
    double c1 = ((double)mu[1] + ((l10 * z0 + l11 * z1)))            * nm;
    double c2 = ((double)mu[2] + ((l20 * z0 + l21 * z1) + l22 * z2)) * nm;

    size_t o = (size_t)(b * N_ + n) * 3;
    float f0 = (float)c0, f1 = (float)c1, f2 = (float)c2;
    out[o + 0] = f0;
    out[o + 1] = f1;
    out[o + 2] = f2;
    if (useF4) {
        float sq = (f0 * f0 + f1 * f1) + f2 * f2;
        mu4[b * N_ + n] = make_float4(f0, f1, f2, sq);
    }
    out[(size_t)B_ * N_ * 12 + (size_t)(b * N_ + n)] = (float)p;   // parent_idx output
}

// one column u of the current 8-batch, read DIRECT FROM GLOBAL (L1/L2-resident 64 KB):
// cp = mu4 + b*N_ (float4 with sq in .w). col = colbase + u*SEGS + seg.
#define LOADU_G(u, SQ) { \
    int col_ = colbase + u * SEGS + seg; \
    float4 q_ = cp[col_]; \
    s##u = fmaf(a00, q_.x, fmaf(a01, q_.y, fmaf(a02, q_.z, q_.w))); \
    r##u = fmaf(a10, q_.x, fmaf(a11, q_.y, fmaf(a12, q_.z, q_.w))); \
    if (SQ) { \
        s##u = (col_ == n0) ? BIGF : s##u; \
        r##u = (col_ == n1) ? BIGF : r##u; } }

// fallback path (no float4 workspace): scalar mu0 reads + inline sq
#define LOADU_S(u, SQ) { \
    int col_ = colbase + u * SEGS + seg; \
    size_t o_ = (size_t)(bN + col_) * 3; \
    float qx_ = mu0[o_], qy_ = mu0[o_+1], qz_ = mu0[o_+2]; \
    float qw_ = (qx_*qx_ + qy_*qy_) + qz_*qz_; \
    s##u = fmaf(a00, qx_, fmaf(a01, qy_, fmaf(a02, qz_, qw_))); \
    r##u = fmaf(a10, qx_, fmaf(a11, qy_, fmaf(a12, qz_, qw_))); \
    if (SQ) { \
        s##u = (col_ == n0) ? BIGF : s##u; \
        r##u = (col_ == n1) ? BIGF : r##u; } }

#define GROUP8(LD, SQ) { \
    float s0,s1,s2,s3,s4,s5,s6,s7, r0,r1,r2,r3,r4,r5,r6,r7; \
    LD(0,SQ) LD(1,SQ) LD(2,SQ) LD(3,SQ) \
    LD(4,SQ) LD(5,SQ) LD(6,SQ) LD(7,SQ) \
    SORT8S(s0,s1,s2,s3,s4,s5,s6,s7) \
    BMERGE8S(ka0,ka1,ka2,ka3,ka4,ka5,ka6,ka7, s0,s1,s2,s3,s4,s5,s6,s7) \
    SORT8S(r0,r1,r2,r3,r4,r5,r6,r7) \
    BMERGE8S(kb0,kb1,kb2,kb3,kb4,kb5,kb6,kb7, r0,r1,r2,r3,r4,r5,r6,r7) }

// ---------------- Kernel 2: kNN — 512 thr, 16 rows/block, NO LDS STAGING ----------------
// mu4 (64 KB/batch, shared by 256 blocks) is L1/L2-resident: staging it through LDS cost
// 8 barrier drains/block and capped residency. Direct global reads + zero inner barriers
// -> 4 blocks/CU x 8 waves schedulable (was ~31% occupancy).
__global__ __launch_bounds__(KTHREADS, 4) void knn_kernel(const float* __restrict__ Sig_p,
                                                          const float* __restrict__ node_mask,
                                                          const float4* __restrict__ mu4,
                                                          int useF4,
                                                          float* __restrict__ out)
{
    __shared__ float  shk[ROWS][8 * 8 + 1];       // 16 x 65 = 4.2 KB wave partials

    int b   = blockIdx.x / (N_ / ROWS);           // 256 blocks per batch
    int rb  = blockIdx.x % (N_ / ROWS);
    int tid = threadIdx.x;
    int slot = tid & (SLOTS - 1);                 // 0..7
    int seg  = tid >> 3;                          // 0..63

    const float* mu0 = out;                       // [B,N,3]
    const float4* cp = mu4 + (size_t)b * N_;
    int bN = b * N_;
    int n0 = rb * ROWS + slot;
    int n1 = n0 + SLOTS;

    float x0, y0, z0v, x1, y1, z1v;
    if (useF4) {
        float4 p0 = cp[n0]; x0 = p0.x; y0 = p0.y; z0v = p0.z;
        float4 p1 = cp[n1]; x1 = p1.x; y1 = p1.y; z1v = p1.z;
    } else {
        size_t so0 = (size_t)(bN + n0) * 3;
        size_t so1 = (size_t)(bN + n1) * 3;
        x0 = mu0[so0]; y0 = mu0[so0+1]; z0v = mu0[so0+2];
        x1 = mu0[so1]; y1 = mu0[so1+1]; z1v = mu0[so1+2];
    }
    float a00 = -2.0f*x0, a01 = -2.0f*y0, a02 = -2.0f*z0v;
    float a10 = -2.0f*x1, a11 = -2.0f*y1, a12 = -2.0f*z1v;

    float ka0=BIGF,ka1=BIGF,ka2=BIGF,ka3=BIGF,ka4=BIGF,ka5=BIGF,ka6=BIGF,ka7=BIGF;
    float kb0=BIGF,kb1=BIGF,kb2=BIGF,kb3=BIGF,kb4=BIGF,kb5=BIGF,kb6=BIGF,kb7=BIGF;

    int selfc = (rb * ROWS) >> 10;                // chunk containing rows n0,n1

    if (useF4) {
        #pragma unroll
        for (int c = 0; c < NCHUNK; ++c) {
            if (c == selfc) {
                { int colbase = c * CHUNK;       GROUP8(LOADU_G, 1) }
                { int colbase = c * CHUNK + 512; GROUP8(LOADU_G, 1) }
            } else {
                { int colbase = c * CHUNK;       GROUP8(LOADU_G, 0) }
                { int colbase = c * CHUNK + 512; GROUP8(LOADU_G, 0) }
            }
        }
    } else {
        #pragma unroll
        for (int c = 0; c < NCHUNK; ++c) {
            if (c == selfc) {
                { int colbase = c * CHUNK;       GROUP8(LOADU_S, 1) }
                { int colbase = c * CHUNK + 512; GROUP8(LOADU_S, 1) }
            } else {
                { int colbase = c * CHUNK;       GROUP8(LOADU_S, 0) }
                { int colbase = c * CHUNK + 512; GROUP8(LOADU_S, 0) }
            }
        }
    }

    // in-wave butterfly merge over the 3 seg bits
    WMERGE(ka0,ka1,ka2,ka3,ka4,ka5,ka6,ka7, 8)
    WMERGE(ka0,ka1,ka2,ka3,ka4,ka5,ka6,ka7, 16)
    WMERGE(ka0,ka1,ka2,ka3,ka4,ka5,ka6,ka7, 32)
    WMERGE(kb0,kb1,kb2,kb3,kb4,kb5,kb6,kb7, 8)
    WMERGE(kb0,kb1,kb2,kb3,kb4,kb5,kb6,kb7, 16)
    WMERGE(kb0,kb1,kb2,kb3,kb4,kb5,kb6,kb7, 32)

    int lane = tid & 63;
    int w    = tid >> 6;                          // wave 0..7
    if (lane < SLOTS) {
        shk[lane][w*8+0] = ka0; shk[lane][w*8+1] = ka1;
        shk[lane][w*8+2] = ka2; shk[lane][w*8+3] = ka3;
        shk[lane][w*8+4] = ka4; shk[lane][w*8+5] = ka5;
        shk[lane][w*8+6] = ka6; shk[lane][w*8+7] = ka7;
        shk[lane+SLOTS][w*8+0] = kb0; shk[lane+SLOTS][w*8+1] = kb1;
        shk[lane+SLOTS][w*8+2] = kb2; shk[lane+SLOTS][w*8+3] = kb3;
        shk[lane+SLOTS][w*8+4] = kb4; shk[lane+SLOTS][w*8+5] = kb5;
        shk[lane+SLOTS][w*8+6] = kb6; shk[lane+SLOTS][w*8+7] = kb7;
    }
    __syncthreads();

    if (tid < ROWS) {                              // one lane per row: 8 sorted lists -> 8
        int r = tid;
        int nn = rb * ROWS + r;
        float e0=BIGF,e1=BIGF,e2=BIGF,e3=BIGF,e4=BIGF,e5=BIGF,e6=BIGF,e7=BIGF;
        #pragma unroll
        for (int w2 = 0; w2 < 8; ++w2) {
            float b0 = shk[r][w2*8+0], b1 = shk[r][w2*8+1];
            float b2 = shk[r][w2*8+2], b3 = shk[r][w2*8+3];
            float b4 = shk[r][w2*8+4], b5 = shk[r][w2*8+5];
            float b6 = shk[r][w2*8+6], b7 = shk[r][w2*8+7];
            BMERGE8S(e0,e1,e2,e3,e4,e5,e6,e7, b0,b1,b2,b3,b4,b5,b6,b7)
        }

        // restore d2 = sqn + s for the selected 8
        float cn;
        if (useF4) {
            cn = cp[nn].w;
        } else {
            size_t so = (size_t)(bN + nn) * 3;
            float xx = mu0[so], yy = mu0[so+1], zz = mu0[so+2];
            cn = (xx*xx + yy*yy) + zz*zz;
        }

        double s0 = sqrt(fmax((double)(cn + e0), 0.0)), s1 = sqrt(fmax((double)(cn + e1), 0.0));
        double s2 = sqrt(fmax((double)(cn + e2), 0.0)), s3 = sqrt(fmax((double)(cn + e3), 0.0));
        double s4 = sqrt(fmax((double)(cn + e4), 0.0)), s5 = sqrt(fmax((double)(cn + e5), 0.0));
        double s6 = sqrt(fmax((double)(cn + e6), 0.0)), s7 = sqrt(fmax((double)(cn + e7), 0.0));
        double d_mean = (((s0 + s1) + (s2 + s3)) + ((s4 + s5) + (s6 + s7))) / 8.0;

        double sigma = fmin(fmax(1.5 * d_mean, 1e-3), 100.0);
        double spacing = sigma * sigma + 1e-6;

        int p = (int)out[(size_t)B_ * N_ * 12 + (size_t)(bN + nn)];
        const float* S = Sig_p + (size_t)(b * K_ + p) * 9;
        double s00 = (double)S[0];
        double s01 = 0.5 * ((double)S[1] + (double)S[3]);
        double s02 = 0.5 * ((double)S[2] + (double)S[6]);
        double s11 = (double)S[4];
        double s12 = 0.5 * ((double)S[5] + (double)S[7]);
        double s22 = (double)S[8];

        const double BETA = 0.85;
        const double OMB  = 1.0 - 0.85;
        double nm = (double)node_mask[bN + nn];

        double d00 = (BETA * (s00 + 1e-6) + OMB * spacing) + 1e-6;
        double d11 = (BETA * (s11 + 1e-6) + OMB * spacing) + 1e-6;
        double d22 = (BETA * (s22 + 1e-6) + OMB * spacing) + 1e-6;
        double o01 = BETA * s01;
        double o02 = BETA * s02;
        double o12 = BETA * s12;

        float* Sg = out + (size_t)B_ * N_ * 3 + (size_t)(bN + nn) * 9;
        Sg[0] = (float)(d00 * nm); Sg[1] = (float)(o01 * nm); Sg[2] = (float)(o02 * nm);
        Sg[3] = (float)(o01 * nm); Sg[4] = (float)(d11 * nm); Sg[5] = (float)(o12 * nm);
        Sg[6] = (float)(o02 * nm); Sg[7] = (float)(o12 * nm); Sg[8] = (float)(d22 * nm);
    }
}

// ---------------- launch ----------------
extern "C" void kernel_launch(void* const* d_in, const int* in_sizes, int n_in,
                              void* d_out, int out_size, void* d_ws, size_t ws_size,
                              hipStream_t stream)
{
    const float* mu_p        = (const float*)d_in[0];
    const float* Sig_p       = (const float*)d_in[1];
    const float* occ         = (const float*)d_in[2];
    const float* mask_parent = (const float*)d_in[3];
    const float* node_mask   = (const float*)d_in[4];
    const float* z           = (const float*)d_in[5];
    float* out = (float*)d_out;

    // float4 mu0 copy (with squared norm in .w) lives in d_ws.
    int useF4 = (ws_size >= (size_t)B_ * N_ * sizeof(float4)) ? 1 : 0;
    float4* mu4 = (float4*)d_ws;

    fused_kernel<<<B_ * 8, 512, 0, stream>>>(mu_p, Sig_p, occ, mask_parent,
                                             node_mask, z, out, mu4, useF4);
    knn_kernel<<<B_ * (N_ / ROWS), KTHREADS, 0, stream>>>(Sig_p, node_mask,
                                                          mu4, useF4, out);
}